// Round 7
// baseline (5063.585 us; speedup 1.0000x reference)
//
#include <hip/hip_runtime.h>
#include <cmath>
#include <stdint.h>

#define NLEV  16
#define TSIZE (1u<<19)
#define PRES  512
#define PFD   8
#define HID   64

struct ResArr { float v[NLEV]; };

__device__ __forceinline__ float4 ld4(const float* p){ return *reinterpret_cast<const float4*>(p); }

__device__ __forceinline__ uint16_t f2bf(float f){
    uint32_t u = __float_as_uint(f);
    uint32_t r = (u + 0x7FFFu + ((u>>16)&1u)) >> 16;
    return (uint16_t)r;
}
__device__ __forceinline__ float bf2f(uint32_t h){ return __uint_as_float(h<<16); }

// acc[o] += wT_col[o] * v (single point)
#define AXPY64(A, WPTR, V) do { const float* _w=(WPTR); const float _v=(V); \
  _Pragma("unroll") \
  for (int _o=0;_o<64;_o+=4){ float4 _w4=ld4(_w+_o); \
    A[_o+0]=fmaf(_w4.x,_v,A[_o+0]); A[_o+1]=fmaf(_w4.y,_v,A[_o+1]); \
    A[_o+2]=fmaf(_w4.z,_v,A[_o+2]); A[_o+3]=fmaf(_w4.w,_v,A[_o+3]); } } while(0)

// two points share one weight fetch: 1 float4 load -> 8 FMAs
#define AXPY64x2(Aa, Ab, WPTR, Va, Vb) do { const float* _w=(WPTR); \
  const float _va=(Va), _vb=(Vb); \
  _Pragma("unroll") \
  for (int _o=0;_o<64;_o+=4){ float4 _w4=ld4(_w+_o); \
    Aa[_o+0]=fmaf(_w4.x,_va,Aa[_o+0]); Ab[_o+0]=fmaf(_w4.x,_vb,Ab[_o+0]); \
    Aa[_o+1]=fmaf(_w4.y,_va,Aa[_o+1]); Ab[_o+1]=fmaf(_w4.y,_vb,Ab[_o+1]); \
    Aa[_o+2]=fmaf(_w4.z,_va,Aa[_o+2]); Ab[_o+2]=fmaf(_w4.z,_vb,Ab[_o+2]); \
    Aa[_o+3]=fmaf(_w4.w,_va,Aa[_o+3]); Ab[_o+3]=fmaf(_w4.w,_vb,Ab[_o+3]); } } while(0)

#define AXPY32x2(Aa, Ab, WPTR, Va, Vb) do { const float* _w=(WPTR); \
  const float _va=(Va), _vb=(Vb); \
  _Pragma("unroll") \
  for (int _o=0;_o<32;_o+=4){ float4 _w4=ld4(_w+_o); \
    Aa[_o+0]=fmaf(_w4.x,_va,Aa[_o+0]); Ab[_o+0]=fmaf(_w4.x,_vb,Ab[_o+0]); \
    Aa[_o+1]=fmaf(_w4.y,_va,Aa[_o+1]); Ab[_o+1]=fmaf(_w4.y,_vb,Ab[_o+1]); \
    Aa[_o+2]=fmaf(_w4.z,_va,Aa[_o+2]); Ab[_o+2]=fmaf(_w4.z,_vb,Ab[_o+2]); \
    Aa[_o+3]=fmaf(_w4.w,_va,Aa[_o+3]); Ab[_o+3]=fmaf(_w4.w,_vb,Ab[_o+3]); } } while(0)

__device__ __forceinline__ void plane_enc(const float* __restrict__ planes,
                                          float p0, float p1, float p2, float* pfv)
{
#pragma unroll
    for (int i=0;i<3;i++){
        float ua = (i==2? p1 : p0)*511.f;
        float va = (i==0? p1 : p2)*511.f;
        float uf=floorf(ua), vf=floorf(va);
        float wu=ua-uf, wv=va-vf;
        int u0=(int)uf; u0 = u0<0?0:(u0>510?510:u0);
        int v0=(int)vf; v0 = v0<0?0:(v0>510?510:v0);
        const float* pl = planes + ((size_t)i*PRES*PRES + (size_t)(u0*PRES+v0))*PFD;
        float4 a0=ld4(pl),              a1=ld4(pl+4);
        float4 b0=ld4(pl+PFD),          b1=ld4(pl+PFD+4);
        float4 c0=ld4(pl+PRES*PFD),     c1=ld4(pl+PRES*PFD+4);
        float4 d0=ld4(pl+PRES*PFD+PFD), d1=ld4(pl+PRES*PFD+PFD+4);
        float w00=(1.f-wu)*(1.f-wv), w01=(1.f-wu)*wv, w10=wu*(1.f-wv), w11=wu*wv;
        pfv[i*8+0]=a0.x*w00+b0.x*w01+c0.x*w10+d0.x*w11;
        pfv[i*8+1]=a0.y*w00+b0.y*w01+c0.y*w10+d0.y*w11;
        pfv[i*8+2]=a0.z*w00+b0.z*w01+c0.z*w10+d0.z*w11;
        pfv[i*8+3]=a0.w*w00+b0.w*w01+c0.w*w10+d0.w*w11;
        pfv[i*8+4]=a1.x*w00+b1.x*w01+c1.x*w10+d1.x*w11;
        pfv[i*8+5]=a1.y*w00+b1.y*w01+c1.y*w10+d1.y*w11;
        pfv[i*8+6]=a1.z*w00+b1.z*w01+c1.z*w10+d1.z*w11;
        pfv[i*8+7]=a1.w*w00+b1.w*w01+c1.w*w10+d1.w*w11;
    }
}

// ===================== K0: level-major hash gather, XCD-pinned =====================
// Launched TWICE (lvl_base = 0 then 8); level = lvl_base + (bid&7) so XCD k's L2
// temporally holds exactly ONE 4MB level table.
__global__ __launch_bounds__(256, 2)
void nerf_k0(const float* __restrict__ x,
             const float* __restrict__ hash_tables,
             uint32_t* __restrict__ feat,
             ResArr res, int npts, int lvl_base)
{
    int bid   = blockIdx.x;
    int level = lvl_base + (bid & 7);
    int chunk = bid >> 3;
    int n0 = chunk*512 + threadIdx.x;
    int n1 = n0 + 256;
    float R = res.v[level];
    const float2* tab = reinterpret_cast<const float2*>(hash_tables) + (size_t)level*TSIZE;

    bool v0ok = (n0 < npts), v1ok = (n1 < npts);

    float p0a=0,p1a=0,p2a=0, p0b=0,p1b=0,p2b=0;
    if (v0ok){ const float* xr = x + (size_t)n0*7;
        p0a=(xr[0]+1.f)*0.5f; p1a=(xr[1]+1.f)*0.5f; p2a=(xr[2]+1.f)*0.5f; }
    if (v1ok){ const float* xr = x + (size_t)n1*7;
        p0b=(xr[0]+1.f)*0.5f; p1b=(xr[1]+1.f)*0.5f; p2b=(xr[2]+1.f)*0.5f; }

    float axa=p0a*R, aya=p1a*R, aza=p2a*R;
    float fxa=floorf(axa), fya=floorf(aya), fza=floorf(aza);
    float rxa=axa-fxa, rya=aya-fya, rza=aza-fza;
    uint32_t ixa=(uint32_t)fxa, iya=(uint32_t)fya, iza=(uint32_t)fza;
    uint32_t hx0a=ixa,             hx1a=ixa+1u;
    uint32_t hy0a=iya*2654435761u, hy1a=(iya+1u)*2654435761u;
    uint32_t hz0a=iza*805459861u,  hz1a=(iza+1u)*805459861u;

    float axb=p0b*R, ayb=p1b*R, azb=p2b*R;
    float fxb=floorf(axb), fyb=floorf(ayb), fzb=floorf(azb);
    float rxb=axb-fxb, ryb=ayb-fyb, rzb=azb-fzb;
    uint32_t ixb=(uint32_t)fxb, iyb=(uint32_t)fyb, izb=(uint32_t)fzb;
    uint32_t hx0b=ixb,             hx1b=ixb+1u;
    uint32_t hy0b=iyb*2654435761u, hy1b=(iyb+1u)*2654435761u;
    uint32_t hz0b=izb*805459861u,  hz1b=(izb+1u)*805459861u;

    float2 ta[8], tb[8];
#pragma unroll
    for (int c=0;c<8;c++){
        uint32_t idx = (((c&4)?hx1a:hx0a) ^ ((c&2)?hy1a:hy0a) ^ ((c&1)?hz1a:hz0a)) & (TSIZE-1u);
        ta[c] = tab[idx];
    }
#pragma unroll
    for (int c=0;c<8;c++){
        uint32_t idx = (((c&4)?hx1b:hx0b) ^ ((c&2)?hy1b:hy0b) ^ ((c&1)?hz1b:hz0b)) & (TSIZE-1u);
        tb[c] = tab[idx];
    }

    float wxa0=1.f-rxa, wya0=1.f-rya, wza0=1.f-rza;
    float f0a=0.f, f1a=0.f;
#pragma unroll
    for (int c=0;c<8;c++){
        float w = ((c&4)?rxa:wxa0)*((c&2)?rya:wya0)*((c&1)?rza:wza0);
        f0a = fmaf(w,ta[c].x,f0a); f1a = fmaf(w,ta[c].y,f1a);
    }
    float wxb0=1.f-rxb, wyb0=1.f-ryb, wzb0=1.f-rzb;
    float f0b=0.f, f1b=0.f;
#pragma unroll
    for (int c=0;c<8;c++){
        float w = ((c&4)?rxb:wxb0)*((c&2)?ryb:wyb0)*((c&1)?rzb:wzb0);
        f0b = fmaf(w,tb[c].x,f0b); f1b = fmaf(w,tb[c].y,f1b);
    }

    size_t base = (size_t)level*npts;
    if (v0ok) feat[base+n0] = (uint32_t)f2bf(f0a) | ((uint32_t)f2bf(f1a)<<16);
    if (v1ok) feat[base+n1] = (uint32_t)f2bf(f0b) | ((uint32_t)f2bf(f1b)<<16);
}

// ===================== ktrans: transpose weights into ws (wT[k][o]) =====================
__global__ void nerf_ktrans(const float* __restrict__ w_sigma0,
                            const float* __restrict__ w_sigma1,
                            const float* __restrict__ w_color0,
                            const float* __restrict__ w_color1,
                            const float* __restrict__ w_color2,
                            float* __restrict__ t_s0, float* __restrict__ t_s1,
                            float* __restrict__ t_c0, float* __restrict__ t_c1,
                            float* __restrict__ t_c2)
{
    int tid = threadIdx.x;
    for (int i=tid;i<56*64; i+=256){ int k=i>>6,o=i&63; t_s0[i]=w_sigma0[o*56+k]; }
    for (int i=tid;i<64*16; i+=256){ int k=i>>4,j=i&15; t_s1[i]=w_sigma1[j*64+k]; }
    for (int i=tid;i<103*64;i+=256){ int k=i>>6,o=i&63; t_c0[i]=w_color0[o*103+k]; }
    for (int i=tid;i<64*64; i+=256){ int k=i>>6,o=i&63; t_c1[i]=w_color1[o*64+k]; }
    for (int i=tid;i<64*4;  i+=256){ int k=i>>2,o=i&3;  t_c2[i]=(o<3)?w_color2[o*64+k]:0.f; }
}

// ===================== kpre: app_pre[a][o] = sum_j embed_a[a][j]*w_color0[o][31+j] =====================
__global__ void nerf_kpre(const float* __restrict__ embed_a,
                          const float* __restrict__ w_color0,
                          float* __restrict__ app_pre)
{
    int a = blockIdx.x;
    int o = threadIdx.x;   // 64
    const float* er = embed_a + (size_t)a*48;
    const float* wr = w_color0 + (size_t)o*103 + 31;
    float s = 0.f;
#pragma unroll
    for (int j=0;j<48;j++) s = fmaf(er[j], wr[j], s);
    app_pre[(size_t)a*64 + o] = s;
}

// ===================== K1s2: sigma MLP, 2 pts/thread, SGPR weights =====================
__global__ __launch_bounds__(256, 1)
void nerf_k1s2(const float* __restrict__ x,
               const float* __restrict__ planes,
               uint32_t* __restrict__ feat,
               const float* __restrict__ wT_s0,
               const float* __restrict__ wT_s1,
               int npts)
{
    int n0 = blockIdx.x*512 + threadIdx.x;
    int n1 = n0 + 256;
    bool aok = (n0 < npts), bok = (n1 < npts);
    if (!aok) return;
    int n1c = bok ? n1 : n0;   // clamp: point b duplicates a if out of range

    float acca[HID], accb[HID];
#pragma unroll
    for (int o=0;o<HID;o++){ acca[o]=0.f; accb[o]=0.f; }

    // hash features
    {
        uint32_t fla[NLEV], flb[NLEV];
#pragma unroll
        for (int l=0;l<NLEV;l++){ fla[l]=feat[(size_t)l*npts+n0]; flb[l]=feat[(size_t)l*npts+n1c]; }
#pragma unroll
        for (int l=0;l<NLEV;l++){
            float f0a = bf2f(fla[l] & 0xFFFFu), f1a = bf2f(fla[l] >> 16);
            float f0b = bf2f(flb[l] & 0xFFFFu), f1b = bf2f(flb[l] >> 16);
            AXPY64x2(acca, accb, &wT_s0[(2*l+0)*64], f0a, f0b);
            AXPY64x2(acca, accb, &wT_s0[(2*l+1)*64], f1a, f1b);
        }
    }

    // planes
    {
        const float* xra = x + (size_t)n0*7;
        const float* xrb = x + (size_t)n1c*7;
        float pfa[24], pfb[24];
        plane_enc(planes, (xra[0]+1.f)*0.5f, (xra[1]+1.f)*0.5f, (xra[2]+1.f)*0.5f, pfa);
        plane_enc(planes, (xrb[0]+1.f)*0.5f, (xrb[1]+1.f)*0.5f, (xrb[2]+1.f)*0.5f, pfb);
#pragma unroll
        for (int j=0;j<24;j++){
            AXPY64x2(acca, accb, &wT_s0[(32+j)*64], pfa[j], pfb[j]);
        }
    }

    // sigma1
    float h1a[16], h1b[16];
#pragma unroll
    for (int j=0;j<16;j++){ h1a[j]=0.f; h1b[j]=0.f; }
#pragma unroll
    for (int k=0;k<HID;k++){
        float va = fmaxf(acca[k], 0.f);
        float vb = fmaxf(accb[k], 0.f);
        const float* wr = &wT_s1[k*16];
#pragma unroll
        for (int j=0;j<16;j+=4){
            float4 w=ld4(wr+j);
            h1a[j+0]=fmaf(w.x,va,h1a[j+0]); h1b[j+0]=fmaf(w.x,vb,h1b[j+0]);
            h1a[j+1]=fmaf(w.y,va,h1a[j+1]); h1b[j+1]=fmaf(w.y,vb,h1b[j+1]);
            h1a[j+2]=fmaf(w.z,va,h1a[j+2]); h1b[j+2]=fmaf(w.z,vb,h1b[j+2]);
            h1a[j+3]=fmaf(w.w,va,h1a[j+3]); h1b[j+3]=fmaf(w.w,vb,h1b[j+3]);
        }
    }
    float sga = fminf(fmaxf(h1a[0], -15.f), 15.f);
    float sgb = fminf(fmaxf(h1b[0], -15.f), 15.f);
    float sigmaa = expf(sga), sigmab = expf(sgb);

#pragma unroll
    for (int l=0;l<15;l++) feat[(size_t)l*npts + n0] = __float_as_uint(h1a[l+1]);
    feat[(size_t)15*npts + n0] = __float_as_uint(sigmaa);
    if (bok){
#pragma unroll
        for (int l=0;l<15;l++) feat[(size_t)l*npts + n1] = __float_as_uint(h1b[l+1]);
        feat[(size_t)15*npts + n1] = __float_as_uint(sigmab);
    }
}

// ===================== K2s2: SH + color MLP, 2 pts/thread, SGPR weights =====================
__global__ __launch_bounds__(256, 1)
void nerf_k2s2(const float* __restrict__ x,
               const float* __restrict__ planes,
               const float* __restrict__ wT_c0,
               const float* __restrict__ wT_c1,
               const float* __restrict__ wT_c2,
               const uint32_t* __restrict__ feat,
               const float* __restrict__ app_pre,
               float* __restrict__ out, int npts)
{
    int n0 = blockIdx.x*512 + threadIdx.x;
    int n1 = n0 + 256;
    bool aok = (n0 < npts), bok = (n1 < npts);
    if (!aok) return;
    int n1c = bok ? n1 : n0;

    const float* xra = x + (size_t)n0*7;
    const float* xrb = x + (size_t)n1c*7;

    float acca[HID], accb[HID];
    // init with app_pre contribution
    {
        int aia = (int)xra[6], aib = (int)xrb[6];
        const float* apa = app_pre + (size_t)aia*64;
        const float* apb = app_pre + (size_t)aib*64;
#pragma unroll
        for (int o=0;o<HID;o+=4){
            float4 va = ld4(apa+o), vb = ld4(apb+o);
            acca[o+0]=va.x; acca[o+1]=va.y; acca[o+2]=va.z; acca[o+3]=va.w;
            accb[o+0]=vb.x; accb[o+1]=vb.y; accb[o+2]=vb.z; accb[o+3]=vb.w;
        }
    }

    // SH(16) both points
    {
        float sha[16], shb[16];
        {
            float dx=xra[3], dy=xra[4], dz=xra[5];
            float nrm = sqrtf(dx*dx+dy*dy+dz*dz);
            float sx=dx/nrm, sy=dy/nrm, sz=dz/nrm;
            float xx=sx*sx, yy=sy*sy, zz=sz*sz, xyv=sx*sy, yzv=sy*sz, xzv=sx*sz;
            sha[0]=0.28209479177387814f;
            sha[1]=-0.48860251190291987f*sy;
            sha[2]= 0.48860251190291987f*sz;
            sha[3]=-0.48860251190291987f*sx;
            sha[4]= 1.0925484305920792f*xyv;
            sha[5]=-1.0925484305920792f*yzv;
            sha[6]= 0.94617469575756f*zz-0.31539156525252005f;
            sha[7]=-1.0925484305920792f*xzv;
            sha[8]= 0.5462742152960396f*(xx-yy);
            sha[9]=-0.5900435899266435f*sy*(3.f*xx-yy);
            sha[10]=2.890611442640554f*xyv*sz;
            sha[11]=-0.4570457994644658f*sy*(4.f*zz-xx-yy);
            sha[12]=0.3731763325901154f*sz*(2.f*zz-3.f*xx-3.f*yy);
            sha[13]=-0.4570457994644658f*sx*(4.f*zz-xx-yy);
            sha[14]=1.445305721320277f*sz*(xx-yy);
            sha[15]=-0.5900435899266435f*sx*(xx-3.f*yy);
        }
        {
            float dx=xrb[3], dy=xrb[4], dz=xrb[5];
            float nrm = sqrtf(dx*dx+dy*dy+dz*dz);
            float sx=dx/nrm, sy=dy/nrm, sz=dz/nrm;
            float xx=sx*sx, yy=sy*sy, zz=sz*sz, xyv=sx*sy, yzv=sy*sz, xzv=sx*sz;
            shb[0]=0.28209479177387814f;
            shb[1]=-0.48860251190291987f*sy;
            shb[2]= 0.48860251190291987f*sz;
            shb[3]=-0.48860251190291987f*sx;
            shb[4]= 1.0925484305920792f*xyv;
            shb[5]=-1.0925484305920792f*yzv;
            shb[6]= 0.94617469575756f*zz-0.31539156525252005f;
            shb[7]=-1.0925484305920792f*xzv;
            shb[8]= 0.5462742152960396f*(xx-yy);
            shb[9]=-0.5900435899266435f*sy*(3.f*xx-yy);
            shb[10]=2.890611442640554f*xyv*sz;
            shb[11]=-0.4570457994644658f*sy*(4.f*zz-xx-yy);
            shb[12]=0.3731763325901154f*sz*(2.f*zz-3.f*xx-3.f*yy);
            shb[13]=-0.4570457994644658f*sx*(4.f*zz-xx-yy);
            shb[14]=1.445305721320277f*sz*(xx-yy);
            shb[15]=-0.5900435899266435f*sx*(xx-3.f*yy);
        }
#pragma unroll
        for (int k=0;k<16;k++){
            AXPY64x2(acca, accb, &wT_c0[k*64], sha[k], shb[k]);
        }
    }

    // geo(15) + sigma
    float sigmaa, sigmab;
    {
        uint32_t ga[16], gb[16];
#pragma unroll
        for (int l=0;l<16;l++){ ga[l]=feat[(size_t)l*npts+n0]; gb[l]=feat[(size_t)l*npts+n1c]; }
        sigmaa = __uint_as_float(ga[15]);
        sigmab = __uint_as_float(gb[15]);
#pragma unroll
        for (int j=0;j<15;j++){
            AXPY64x2(acca, accb, &wT_c0[(16+j)*64],
                     __uint_as_float(ga[j]), __uint_as_float(gb[j]));
        }
    }

    // planes
    {
        float pfa[24], pfb[24];
        plane_enc(planes, (xra[0]+1.f)*0.5f, (xra[1]+1.f)*0.5f, (xra[2]+1.f)*0.5f, pfa);
        plane_enc(planes, (xrb[0]+1.f)*0.5f, (xrb[1]+1.f)*0.5f, (xrb[2]+1.f)*0.5f, pfb);
#pragma unroll
        for (int j=0;j<24;j++){
            AXPY64x2(acca, accb, &wT_c0[(79+j)*64], pfa[j], pfb[j]);
        }
    }

#pragma unroll
    for (int k=0;k<HID;k++){ acca[k]=fmaxf(acca[k],0.f); accb[k]=fmaxf(accb[k],0.f); }

    // color1 + color2, 2x32-output passes
    float c0a=0.f, c1a=0.f, c2a=0.f;
    float c0b=0.f, c1b=0.f, c2b=0.f;
    {
        float ha[32], hb[32];
#pragma unroll
        for (int o=0;o<32;o++){ ha[o]=0.f; hb[o]=0.f; }
#pragma unroll
        for (int k=0;k<HID;k++){
            AXPY32x2(ha, hb, &wT_c1[k*64], acca[k], accb[k]);
        }
#pragma unroll
        for (int o=0;o<32;o++){
            float va = fmaxf(ha[o],0.f), vb = fmaxf(hb[o],0.f);
            float4 w = ld4(&wT_c2[o*4]);
            c0a=fmaf(w.x,va,c0a); c1a=fmaf(w.y,va,c1a); c2a=fmaf(w.z,va,c2a);
            c0b=fmaf(w.x,vb,c0b); c1b=fmaf(w.y,vb,c1b); c2b=fmaf(w.z,vb,c2b);
        }
    }
    {
        float ha[32], hb[32];
#pragma unroll
        for (int o=0;o<32;o++){ ha[o]=0.f; hb[o]=0.f; }
#pragma unroll
        for (int k=0;k<HID;k++){
            AXPY32x2(ha, hb, &wT_c1[k*64+32], acca[k], accb[k]);
        }
#pragma unroll
        for (int o=0;o<32;o++){
            float va = fmaxf(ha[o],0.f), vb = fmaxf(hb[o],0.f);
            float4 w = ld4(&wT_c2[(32+o)*4]);
            c0a=fmaf(w.x,va,c0a); c1a=fmaf(w.y,va,c1a); c2a=fmaf(w.z,va,c2a);
            c0b=fmaf(w.x,vb,c0b); c1b=fmaf(w.y,vb,c1b); c2b=fmaf(w.z,vb,c2b);
        }
    }

    float4 o4a;
    o4a.x = 1.f/(1.f+expf(-c0a));
    o4a.y = 1.f/(1.f+expf(-c1a));
    o4a.z = 1.f/(1.f+expf(-c2a));
    o4a.w = sigmaa;
    *reinterpret_cast<float4*>(out + (size_t)n0*4) = o4a;
    if (bok){
        float4 o4b;
        o4b.x = 1.f/(1.f+expf(-c0b));
        o4b.y = 1.f/(1.f+expf(-c1b));
        o4b.z = 1.f/(1.f+expf(-c2b));
        o4b.w = sigmab;
        *reinterpret_cast<float4*>(out + (size_t)n1*4) = o4b;
    }
}

// ===================== fallback single kernel (used only if ws too small) =====================
__global__ __launch_bounds__(256, 1)
void nerf_fwd(const float* __restrict__ x,
              const float* __restrict__ hash_tables,
              const float* __restrict__ planes,
              const float* __restrict__ embed_a,
              const float* __restrict__ w_sigma0,
              const float* __restrict__ w_sigma1,
              const float* __restrict__ w_color0,
              const float* __restrict__ w_color1,
              const float* __restrict__ w_color2,
              float* __restrict__ out,
              ResArr res, int npts)
{
    __shared__ float s_ws0T[56*64];
    __shared__ float s_ws1T[64*16];
    __shared__ float s_wc0T[103*64];
    __shared__ float s_wc1T[64*64];
    __shared__ float s_wc2T[64*4];

    for (int i = threadIdx.x; i < 56*64;  i += 256){ int k=i>>6, o=i&63; s_ws0T[i] = w_sigma0[o*56+k]; }
    for (int i = threadIdx.x; i < 64*16;  i += 256){ int k=i>>4, j=i&15; s_ws1T[i] = w_sigma1[j*64+k]; }
    for (int i = threadIdx.x; i < 103*64; i += 256){ int k=i>>6, o=i&63; s_wc0T[i] = w_color0[o*103+k]; }
    for (int i = threadIdx.x; i < 64*64;  i += 256){ int k=i>>6, o=i&63; s_wc1T[i] = w_color1[o*64+k]; }
    for (int i = threadIdx.x; i < 64*4;   i += 256){ int k=i>>2, o=i&3;  s_wc2T[i] = (o<3)? w_color2[o*64+k] : 0.f; }
    __syncthreads();

    int n = blockIdx.x*256 + threadIdx.x;
    if (n >= npts) return;

    const float* xr = x + (size_t)n*7;
    float px=xr[0], py=xr[1], pz=xr[2];
    float dx=xr[3], dy=xr[4], dz=xr[5];
    float appf = xr[6];
    float p0=(px+1.f)*0.5f, p1=(py+1.f)*0.5f, p2=(pz+1.f)*0.5f;

    float acc[HID];
#pragma unroll
    for (int o=0;o<HID;o++) acc[o]=0.f;

    const float2* tabs = reinterpret_cast<const float2*>(hash_tables);
    for (int l=0; l<NLEV; l++){
        float R = res.v[l];
        float ax=p0*R, ay=p1*R, az=p2*R;
        float fx=floorf(ax), fy=floorf(ay), fz=floorf(az);
        float rx=ax-fx, ry=ay-fy, rz=az-fz;
        uint32_t ix=(uint32_t)fx, iy=(uint32_t)fy, iz=(uint32_t)fz;
        const float2* tab = tabs + (size_t)l*TSIZE;
        uint32_t hx0=ix,               hx1=ix+1u;
        uint32_t hy0=iy*2654435761u,   hy1=(iy+1u)*2654435761u;
        uint32_t hz0=iz*805459861u,    hz1=(iz+1u)*805459861u;
        float wx0=1.f-rx, wx1=rx, wy0=1.f-ry, wy1=ry, wz0=1.f-rz, wz1=rz;
        float f0=0.f, f1=0.f;
#pragma unroll
        for (int c=0;c<8;c++){
            uint32_t hxx=(c&4)?hx1:hx0;
            uint32_t hyy=(c&2)?hy1:hy0;
            uint32_t hzz=(c&1)?hz1:hz0;
            uint32_t idx=(hxx^hyy^hzz)&(TSIZE-1u);
            float2 t = tab[idx];
            float w = ((c&4)?wx1:wx0)*((c&2)?wy1:wy0)*((c&1)?wz1:wz0);
            f0 = fmaf(w,t.x,f0);
            f1 = fmaf(w,t.y,f1);
        }
        AXPY64(acc, &s_ws0T[(2*l+0)*64], f0);
        AXPY64(acc, &s_ws0T[(2*l+1)*64], f1);
    }

    float pfv[24];
    plane_enc(planes, p0, p1, p2, pfv);
#pragma unroll
    for (int j=0;j<24;j++){
        AXPY64(acc, &s_ws0T[(32+j)*64], pfv[j]);
    }

    float h1[16];
#pragma unroll
    for (int j=0;j<16;j++) h1[j]=0.f;
#pragma unroll
    for (int k=0;k<HID;k++){
        float v = fmaxf(acc[k], 0.f);
        const float* wr = &s_ws1T[k*16];
#pragma unroll
        for (int j=0;j<16;j+=4){
            float4 w=ld4(wr+j);
            h1[j+0]=fmaf(w.x,v,h1[j+0]); h1[j+1]=fmaf(w.y,v,h1[j+1]);
            h1[j+2]=fmaf(w.z,v,h1[j+2]); h1[j+3]=fmaf(w.w,v,h1[j+3]);
        }
    }
    float sg = fminf(fmaxf(h1[0], -15.f), 15.f);
    float sigma = expf(sg);

#pragma unroll
    for (int o=0;o<HID;o++) acc[o]=0.f;

    float nrm = sqrtf(dx*dx+dy*dy+dz*dz);
    float sx=dx/nrm, sy=dy/nrm, sz=dz/nrm;
    float xx=sx*sx, yy=sy*sy, zz=sz*sz, xyv=sx*sy, yzv=sy*sz, xzv=sx*sz;
    float sh[16];
    sh[0]=0.28209479177387814f;
    sh[1]=-0.48860251190291987f*sy;
    sh[2]= 0.48860251190291987f*sz;
    sh[3]=-0.48860251190291987f*sx;
    sh[4]= 1.0925484305920792f*xyv;
    sh[5]=-1.0925484305920792f*yzv;
    sh[6]= 0.94617469575756f*zz-0.31539156525252005f;
    sh[7]=-1.0925484305920792f*xzv;
    sh[8]= 0.5462742152960396f*(xx-yy);
    sh[9]=-0.5900435899266435f*sy*(3.f*xx-yy);
    sh[10]=2.890611442640554f*xyv*sz;
    sh[11]=-0.4570457994644658f*sy*(4.f*zz-xx-yy);
    sh[12]=0.3731763325901154f*sz*(2.f*zz-3.f*xx-3.f*yy);
    sh[13]=-0.4570457994644658f*sx*(4.f*zz-xx-yy);
    sh[14]=1.445305721320277f*sz*(xx-yy);
    sh[15]=-0.5900435899266435f*sx*(xx-3.f*yy);
#pragma unroll
    for (int k=0;k<16;k++){
        AXPY64(acc, &s_wc0T[k*64], sh[k]);
    }
#pragma unroll
    for (int j=0;j<15;j++){
        AXPY64(acc, &s_wc0T[(16+j)*64], h1[1+j]);
    }
    {
        int ai = (int)appf;
        const float* ar = embed_a + (size_t)ai*48;
        for (int q=0;q<12;q++){
            float4 av = ld4(ar + q*4);
            const float* wc = &s_wc0T[(31+q*4)*64];
            AXPY64(acc, wc,       av.x);
            AXPY64(acc, wc+64,    av.y);
            AXPY64(acc, wc+128,   av.z);
            AXPY64(acc, wc+192,   av.w);
        }
    }
#pragma unroll
    for (int j=0;j<24;j++){
        AXPY64(acc, &s_wc0T[(79+j)*64], pfv[j]);
    }

    float acc2[HID];
#pragma unroll
    for (int o=0;o<HID;o++) acc2[o]=0.f;
#pragma unroll
    for (int k=0;k<HID;k++){
        float v = fmaxf(acc[k], 0.f);
        AXPY64(acc2, &s_wc1T[k*64], v);
    }

    float c0a=0.f, c1a=0.f, c2a=0.f;
#pragma unroll
    for (int k=0;k<HID;k++){
        float v = fmaxf(acc2[k], 0.f);
        float4 w = ld4(&s_wc2T[k*4]);
        c0a=fmaf(w.x,v,c0a); c1a=fmaf(w.y,v,c1a); c2a=fmaf(w.z,v,c2a);
    }
    float4 o4;
    o4.x = 1.f/(1.f+expf(-c0a));
    o4.y = 1.f/(1.f+expf(-c1a));
    o4.z = 1.f/(1.f+expf(-c2a));
    o4.w = sigma;
    *reinterpret_cast<float4*>(out + (size_t)n*4) = o4;
}

extern "C" void kernel_launch(void* const* d_in, const int* in_sizes, int n_in,
                              void* d_out, int out_size, void* d_ws, size_t ws_size,
                              hipStream_t stream) {
    const float* x        = (const float*)d_in[0];
    const float* ht       = (const float*)d_in[1];
    const float* planes   = (const float*)d_in[2];
    const float* embed_a  = (const float*)d_in[3];
    const float* w_sigma0 = (const float*)d_in[4];
    const float* w_sigma1 = (const float*)d_in[5];
    const float* w_color0 = (const float*)d_in[6];
    const float* w_color1 = (const float*)d_in[7];
    const float* w_color2 = (const float*)d_in[8];
    float* out = (float*)d_out;

    int npts = in_sizes[0] / 7;

    // Replicate numpy's RES bit-exactly (same libm chain).
    ResArr res;
    double b = exp((log(2048.0) - log(16.0)) / 15.0);
    for (int l=0; l<NLEV; l++)
        res.v[l] = (float)floor(16.0 * pow(b, (double)l));

    // ws layout: [wT block + app_pre (324352 B)] [feat: npts*16*4 B]
    const size_t F_S0 = 56*64, F_S1 = 64*16, F_C0 = 103*64, F_C1 = 64*64, F_C2 = 64*4;
    const size_t small_floats = F_S0+F_S1+F_C0+F_C1+F_C2 + 1024*64;  // 81088
    const size_t small_bytes  = small_floats*4;                       // 324352
    size_t feat_bytes = (size_t)npts * 16 * sizeof(uint32_t);

    if (ws_size >= small_bytes + feat_bytes) {
        float* f     = (float*)d_ws;
        float* t_s0  = f;
        float* t_s1  = t_s0 + F_S0;
        float* t_c0  = t_s1 + F_S1;
        float* t_c1  = t_c0 + F_C0;
        float* t_c2  = t_c1 + F_C1;
        float* a_pre = t_c2 + F_C2;
        uint32_t* feat = (uint32_t*)((char*)d_ws + small_bytes);

        hipLaunchKernelGGL(nerf_ktrans, dim3(1), dim3(256), 0, stream,
                           w_sigma0, w_sigma1, w_color0, w_color1, w_color2,
                           t_s0, t_s1, t_c0, t_c1, t_c2);
        hipLaunchKernelGGL(nerf_kpre, dim3(1024), dim3(64), 0, stream,
                           embed_a, w_color0, a_pre);

        int chunks = (npts + 511) / 512;
        hipLaunchKernelGGL(nerf_k0, dim3(8*chunks), dim3(256), 0, stream,
                           x, ht, feat, res, npts, 0);
        hipLaunchKernelGGL(nerf_k0, dim3(8*chunks), dim3(256), 0, stream,
                           x, ht, feat, res, npts, 8);

        int g2 = (npts + 511) / 512;
        hipLaunchKernelGGL(nerf_k1s2, dim3(g2), dim3(256), 0, stream,
                           x, planes, feat, t_s0, t_s1, npts);
        hipLaunchKernelGGL(nerf_k2s2, dim3(g2), dim3(256), 0, stream,
                           x, planes, t_c0, t_c1, t_c2, feat, a_pre, out, npts);
    } else {
        int grid = (npts + 255) / 256;
        hipLaunchKernelGGL(nerf_fwd, dim3(grid), dim3(256), 0, stream,
                           x, ht, planes, embed_a,
                           w_sigma0, w_sigma1, w_color0, w_color1, w_color2,
                           out, res, npts);
    }
}

// Round 8
// 999.665 us; speedup vs baseline: 5.0653x; 5.0653x over previous
//
#include <hip/hip_runtime.h>
#include <cmath>
#include <stdint.h>

#define NLEV  16
#define TSIZE (1u<<19)
#define PRES  512
#define PFD   8
#define HID   64
#define LDSH  72   // short stride per point row in k2m LDS (pad for banks)

struct ResArr { float v[NLEV]; };

typedef __attribute__((ext_vector_type(8))) short short8v;   // 8 bf16 (4 VGPRs)
typedef __attribute__((ext_vector_type(4))) float f32x4;

__device__ __forceinline__ float4 ld4(const float* p){ return *reinterpret_cast<const float4*>(p); }

__device__ __forceinline__ uint16_t f2bf(float f){
    uint32_t u = __float_as_uint(f);
    uint32_t r = (u + 0x7FFFu + ((u>>16)&1u)) >> 16;
    return (uint16_t)r;
}
__device__ __forceinline__ float bf2f(uint32_t h){ return __uint_as_float(h<<16); }

// acc[o] += wT_col[o] * v (single point), static indexing
#define AXPY64(A, WPTR, V) do { const float* _w=(WPTR); const float _v=(V); \
  _Pragma("unroll") \
  for (int _o=0;_o<64;_o+=4){ float4 _w4=ld4(_w+_o); \
    A[_o+0]=fmaf(_w4.x,_v,A[_o+0]); A[_o+1]=fmaf(_w4.y,_v,A[_o+1]); \
    A[_o+2]=fmaf(_w4.z,_v,A[_o+2]); A[_o+3]=fmaf(_w4.w,_v,A[_o+3]); } } while(0)

__device__ __forceinline__ void plane_enc(const float* __restrict__ planes,
                                          float p0, float p1, float p2, float* pfv)
{
#pragma unroll
    for (int i=0;i<3;i++){
        float ua = (i==2? p1 : p0)*511.f;
        float va = (i==0? p1 : p2)*511.f;
        float uf=floorf(ua), vf=floorf(va);
        float wu=ua-uf, wv=va-vf;
        int u0=(int)uf; u0 = u0<0?0:(u0>510?510:u0);
        int v0=(int)vf; v0 = v0<0?0:(v0>510?510:v0);
        const float* pl = planes + ((size_t)i*PRES*PRES + (size_t)(u0*PRES+v0))*PFD;
        float4 a0=ld4(pl),              a1=ld4(pl+4);
        float4 b0=ld4(pl+PFD),          b1=ld4(pl+PFD+4);
        float4 c0=ld4(pl+PRES*PFD),     c1=ld4(pl+PRES*PFD+4);
        float4 d0=ld4(pl+PRES*PFD+PFD), d1=ld4(pl+PRES*PFD+PFD+4);
        float w00=(1.f-wu)*(1.f-wv), w01=(1.f-wu)*wv, w10=wu*(1.f-wv), w11=wu*wv;
        pfv[i*8+0]=a0.x*w00+b0.x*w01+c0.x*w10+d0.x*w11;
        pfv[i*8+1]=a0.y*w00+b0.y*w01+c0.y*w10+d0.y*w11;
        pfv[i*8+2]=a0.z*w00+b0.z*w01+c0.z*w10+d0.z*w11;
        pfv[i*8+3]=a0.w*w00+b0.w*w01+c0.w*w10+d0.w*w11;
        pfv[i*8+4]=a1.x*w00+b1.x*w01+c1.x*w10+d1.x*w11;
        pfv[i*8+5]=a1.y*w00+b1.y*w01+c1.y*w10+d1.y*w11;
        pfv[i*8+6]=a1.z*w00+b1.z*w01+c1.z*w10+d1.z*w11;
        pfv[i*8+7]=a1.w*w00+b1.w*w01+c1.w*w10+d1.w*w11;
    }
}

// ===================== K0: level-major hash gather, XCD-pinned (R6-verified) =====================
__global__ __launch_bounds__(256, 2)
void nerf_k0(const float* __restrict__ x,
             const float* __restrict__ hash_tables,
             uint32_t* __restrict__ feat,
             ResArr res, int npts, int lvl_base)
{
    int bid   = blockIdx.x;
    int level = lvl_base + (bid & 7);
    int chunk = bid >> 3;
    int n0 = chunk*512 + threadIdx.x;
    int n1 = n0 + 256;
    float R = res.v[level];
    const float2* tab = reinterpret_cast<const float2*>(hash_tables) + (size_t)level*TSIZE;

    bool v0ok = (n0 < npts), v1ok = (n1 < npts);

    float p0a=0,p1a=0,p2a=0, p0b=0,p1b=0,p2b=0;
    if (v0ok){ const float* xr = x + (size_t)n0*7;
        p0a=(xr[0]+1.f)*0.5f; p1a=(xr[1]+1.f)*0.5f; p2a=(xr[2]+1.f)*0.5f; }
    if (v1ok){ const float* xr = x + (size_t)n1*7;
        p0b=(xr[0]+1.f)*0.5f; p1b=(xr[1]+1.f)*0.5f; p2b=(xr[2]+1.f)*0.5f; }

    float axa=p0a*R, aya=p1a*R, aza=p2a*R;
    float fxa=floorf(axa), fya=floorf(aya), fza=floorf(aza);
    float rxa=axa-fxa, rya=aya-fya, rza=aza-fza;
    uint32_t ixa=(uint32_t)fxa, iya=(uint32_t)fya, iza=(uint32_t)fza;
    uint32_t hx0a=ixa,             hx1a=ixa+1u;
    uint32_t hy0a=iya*2654435761u, hy1a=(iya+1u)*2654435761u;
    uint32_t hz0a=iza*805459861u,  hz1a=(iza+1u)*805459861u;

    float axb=p0b*R, ayb=p1b*R, azb=p2b*R;
    float fxb=floorf(axb), fyb=floorf(ayb), fzb=floorf(azb);
    float rxb=axb-fxb, ryb=ayb-fyb, rzb=azb-fzb;
    uint32_t ixb=(uint32_t)fxb, iyb=(uint32_t)fyb, izb=(uint32_t)fzb;
    uint32_t hx0b=ixb,             hx1b=ixb+1u;
    uint32_t hy0b=iyb*2654435761u, hy1b=(iyb+1u)*2654435761u;
    uint32_t hz0b=izb*805459861u,  hz1b=(izb+1u)*805459861u;

    float2 ta[8], tb[8];
#pragma unroll
    for (int c=0;c<8;c++){
        uint32_t idx = (((c&4)?hx1a:hx0a) ^ ((c&2)?hy1a:hy0a) ^ ((c&1)?hz1a:hz0a)) & (TSIZE-1u);
        ta[c] = tab[idx];
    }
#pragma unroll
    for (int c=0;c<8;c++){
        uint32_t idx = (((c&4)?hx1b:hx0b) ^ ((c&2)?hy1b:hy0b) ^ ((c&1)?hz1b:hz0b)) & (TSIZE-1u);
        tb[c] = tab[idx];
    }

    float wxa0=1.f-rxa, wya0=1.f-rya, wza0=1.f-rza;
    float f0a=0.f, f1a=0.f;
#pragma unroll
    for (int c=0;c<8;c++){
        float w = ((c&4)?rxa:wxa0)*((c&2)?rya:wya0)*((c&1)?rza:wza0);
        f0a = fmaf(w,ta[c].x,f0a); f1a = fmaf(w,ta[c].y,f1a);
    }
    float wxb0=1.f-rxb, wyb0=1.f-ryb, wzb0=1.f-rzb;
    float f0b=0.f, f1b=0.f;
#pragma unroll
    for (int c=0;c<8;c++){
        float w = ((c&4)?rxb:wxb0)*((c&2)?ryb:wyb0)*((c&1)?rzb:wzb0);
        f0b = fmaf(w,tb[c].x,f0b); f1b = fmaf(w,tb[c].y,f1b);
    }

    size_t base = (size_t)level*npts;
    if (v0ok) feat[base+n0] = (uint32_t)f2bf(f0a) | ((uint32_t)f2bf(f1a)<<16);
    if (v1ok) feat[base+n1] = (uint32_t)f2bf(f0b) | ((uint32_t)f2bf(f1b)<<16);
}

// ===================== ktrans: weight prep =====================
// t_s0/t_s1: fp32 transposed (K1s VALU path).
// c0B/c1B: bf16 hi/lo B-fragments for MFMA. Layout idx = nt*1024 + ks*512 + l*8 + i;
// value = w[out = nt*16+(l&15)][k = ks*32+(l>>4)*8+i] per MFMA B mapping (col=l&15).
__global__ void nerf_ktrans(const float* __restrict__ w_sigma0,
                            const float* __restrict__ w_sigma1,
                            const float* __restrict__ w_color0,
                            const float* __restrict__ w_color1,
                            const float* __restrict__ w_color2,
                            float* __restrict__ t_s0, float* __restrict__ t_s1,
                            float* __restrict__ t_c2,
                            short* __restrict__ c0Bhi, short* __restrict__ c0Blo,
                            short* __restrict__ c1Bhi, short* __restrict__ c1Blo)
{
    int tid = threadIdx.x;
    for (int i=tid;i<56*64; i+=256){ int k=i>>6,o=i&63; t_s0[i]=w_sigma0[o*56+k]; }
    for (int i=tid;i<64*16; i+=256){ int k=i>>4,j=i&15; t_s1[i]=w_sigma1[j*64+k]; }
    for (int i=tid;i<64*4;  i+=256){ int k=i>>2,o=i&3;  t_c2[i]=(o<3)?w_color2[o*64+k]:0.f; }

    for (int idx=tid; idx<4096; idx+=256){
        int nt = idx >> 10;
        int r1 = idx & 1023;
        int ks = r1 >> 9;
        int r2 = r1 & 511;
        int l  = r2 >> 3;
        int i  = r2 & 7;
        int out = nt*16 + (l & 15);
        int kk  = ks*32 + (l >> 4)*8 + i;
        // color0: K-order sh(0..15)->col kk, geo(16..30)->col kk, pf(31..54)->col kk+48, pad->0
        float w0 = 0.f;
        if (kk < 31)       w0 = w_color0[out*103 + kk];
        else if (kk < 55)  w0 = w_color0[out*103 + kk + 48];
        uint16_t h0 = f2bf(w0);
        uint16_t l0 = f2bf(w0 - bf2f(h0));
        c0Bhi[idx] = (short)h0; c0Blo[idx] = (short)l0;
        // color1: K = 64 direct
        float w1 = w_color1[out*64 + kk];
        uint16_t h1 = f2bf(w1);
        uint16_t l1 = f2bf(w1 - bf2f(h1));
        c1Bhi[idx] = (short)h1; c1Blo[idx] = (short)l1;
    }
}

// ===================== kpre: app_pre[a][o] =====================
__global__ void nerf_kpre(const float* __restrict__ embed_a,
                          const float* __restrict__ w_color0,
                          float* __restrict__ app_pre)
{
    int a = blockIdx.x;
    int o = threadIdx.x;   // 64
    const float* er = embed_a + (size_t)a*48;
    const float* wr = w_color0 + (size_t)o*103 + 31;
    float s = 0.f;
#pragma unroll
    for (int j=0;j<48;j++) s = fmaf(er[j], wr[j], s);
    app_pre[(size_t)a*64 + o] = s;
}

// ===================== K1s: sigma MLP (R6-verified VALU path) =====================
__global__ __launch_bounds__(256, 2)
void nerf_k1s(const float* __restrict__ x,
              const float* __restrict__ planes,
              uint32_t* __restrict__ feat,
              const float* __restrict__ wT_s0,
              const float* __restrict__ wT_s1,
              int npts)
{
    int n = blockIdx.x*256 + threadIdx.x;
    if (n >= npts) return;

    uint32_t fl[NLEV];
#pragma unroll
    for (int l=0;l<NLEV;l++) fl[l] = feat[(size_t)l*npts + n];

    float acc[HID];
#pragma unroll
    for (int o=0;o<HID;o++) acc[o]=0.f;

#pragma unroll
    for (int l=0;l<NLEV;l++){
        float f0 = bf2f(fl[l] & 0xFFFFu);
        float f1 = bf2f(fl[l] >> 16);
        AXPY64(acc, &wT_s0[(2*l+0)*64], f0);
        AXPY64(acc, &wT_s0[(2*l+1)*64], f1);
    }

    const float* xr = x + (size_t)n*7;
    float p0=(xr[0]+1.f)*0.5f, p1=(xr[1]+1.f)*0.5f, p2=(xr[2]+1.f)*0.5f;
    float pfv[24];
    plane_enc(planes, p0, p1, p2, pfv);
#pragma unroll
    for (int j=0;j<24;j++){
        AXPY64(acc, &wT_s0[(32+j)*64], pfv[j]);
    }

    float h1[16];
#pragma unroll
    for (int j=0;j<16;j++) h1[j]=0.f;
#pragma unroll
    for (int k=0;k<HID;k++){
        float v = fmaxf(acc[k], 0.f);
        const float* wr = &wT_s1[k*16];
#pragma unroll
        for (int j=0;j<16;j+=4){
            float4 w=ld4(wr+j);
            h1[j+0]=fmaf(w.x,v,h1[j+0]); h1[j+1]=fmaf(w.y,v,h1[j+1]);
            h1[j+2]=fmaf(w.z,v,h1[j+2]); h1[j+3]=fmaf(w.w,v,h1[j+3]);
        }
    }
    float sg = fminf(fmaxf(h1[0], -15.f), 15.f);
    float sigma = expf(sg);

#pragma unroll
    for (int l=0;l<15;l++) feat[(size_t)l*npts + n] = __float_as_uint(h1[l+1]);
    feat[(size_t)15*npts + n] = __float_as_uint(sigma);
}

// ===================== K2m: color MLP via bf16-split MFMA =====================
// One wave (64 threads) per 64 points. C[pt][out] = act[pt][k] * w[out][k].
// MFMA 16x16x32_bf16 layouts (guide §3, m89-verified C/D):
//   A: row=l&15, k=(l>>4)*8+i ; B: col=l&15, k=(l>>4)*8+i ; D: col=l&15, row=(l>>4)*4+r
// acc split: D = Ah*Bh + Ah*Bl + Al*Bh (lo*lo dropped, ~2^-18 rel).
__global__ __launch_bounds__(64, 1)
void nerf_k2m(const float* __restrict__ x,
              const float* __restrict__ planes,
              const uint32_t* __restrict__ feat,
              const float* __restrict__ app_pre,
              const short* __restrict__ c0Bhi, const short* __restrict__ c0Blo,
              const short* __restrict__ c1Bhi, const short* __restrict__ c1Blo,
              const float* __restrict__ t_c2,
              float* __restrict__ out, int npts)
{
    __shared__ uint16_t ldsA[2*64*LDSH];   // hi plane [0..64*LDSH), lo plane after
    __shared__ int      lds_ai[64];

    const int l = threadIdx.x;
    int n = blockIdx.x*64 + l;
    bool ok = (n < npts);
    int nc = ok ? n : (npts-1);
    const float* xr = x + (size_t)nc*7;

    // ---------- phase 1: activations -> LDS (bf16 hi/lo) ----------
    {
        float av[55];
        // SH(16)
        float dx=xr[3], dy=xr[4], dz=xr[5];
        float nrm = sqrtf(dx*dx+dy*dy+dz*dz);
        float sx=dx/nrm, sy=dy/nrm, sz=dz/nrm;
        float xx=sx*sx, yy=sy*sy, zz=sz*sz, xyv=sx*sy, yzv=sy*sz, xzv=sx*sz;
        av[0]=0.28209479177387814f;
        av[1]=-0.48860251190291987f*sy;
        av[2]= 0.48860251190291987f*sz;
        av[3]=-0.48860251190291987f*sx;
        av[4]= 1.0925484305920792f*xyv;
        av[5]=-1.0925484305920792f*yzv;
        av[6]= 0.94617469575756f*zz-0.31539156525252005f;
        av[7]=-1.0925484305920792f*xzv;
        av[8]= 0.5462742152960396f*(xx-yy);
        av[9]=-0.5900435899266435f*sy*(3.f*xx-yy);
        av[10]=2.890611442640554f*xyv*sz;
        av[11]=-0.4570457994644658f*sy*(4.f*zz-xx-yy);
        av[12]=0.3731763325901154f*sz*(2.f*zz-3.f*xx-3.f*yy);
        av[13]=-0.4570457994644658f*sx*(4.f*zz-xx-yy);
        av[14]=1.445305721320277f*sz*(xx-yy);
        av[15]=-0.5900435899266435f*sx*(xx-3.f*yy);
        // geo(15) from feat slots 0..14 (fp32)
#pragma unroll
        for (int j=0;j<15;j++) av[16+j] = __uint_as_float(feat[(size_t)j*npts + nc]);
        // pf(24)
        float pfv[24];
        plane_enc(planes, (xr[0]+1.f)*0.5f, (xr[1]+1.f)*0.5f, (xr[2]+1.f)*0.5f, pfv);
#pragma unroll
        for (int j=0;j<24;j++) av[31+j] = pfv[j];

        uint16_t* rh = &ldsA[l*LDSH];
        uint16_t* rl = &ldsA[64*LDSH + l*LDSH];
#pragma unroll
        for (int kk=0; kk<64; kk++){
            float a = (kk<55) ? av[kk] : 0.f;
            uint16_t hi = f2bf(a);
            uint16_t lo = f2bf(a - bf2f(hi));
            rh[kk] = hi; rl[kk] = lo;
        }
        lds_ai[l] = (int)xr[6];
    }
    __syncthreads();

    // ---------- phase 2: acc init from app_pre, color0 MFMA ----------
    f32x4 acc[4][4];
    {
        const int lq = l >> 4, lr = l & 15;
#pragma unroll
        for (int mt=0; mt<4; mt++){
#pragma unroll
            for (int r=0; r<4; r++){
                int ai = lds_ai[mt*16 + lq*4 + r];
                const float* ap = app_pre + (size_t)ai*64 + lr;
#pragma unroll
                for (int nt=0; nt<4; nt++)
                    acc[mt][nt][r] = ap[nt*16];
            }
        }
    }
    {
        const int lq = l >> 4, lr = l & 15;
#pragma unroll
        for (int ks=0; ks<2; ks++){
            short8v ah[4], al[4];
#pragma unroll
            for (int mt=0; mt<4; mt++){
                const uint16_t* ph = &ldsA[(mt*16+lr)*LDSH + ks*32 + lq*8];
                ah[mt] = *reinterpret_cast<const short8v*>(ph);
                al[mt] = *reinterpret_cast<const short8v*>(ph + 64*LDSH);
            }
#pragma unroll
            for (int nt=0; nt<4; nt++){
                short8v bh = *reinterpret_cast<const short8v*>(&c0Bhi[(nt*2+ks)*512 + l*8]);
                short8v bl = *reinterpret_cast<const short8v*>(&c0Blo[(nt*2+ks)*512 + l*8]);
#pragma unroll
                for (int mt=0; mt<4; mt++){
                    acc[mt][nt] = __builtin_amdgcn_mfma_f32_16x16x32_bf16(ah[mt], bh, acc[mt][nt], 0,0,0);
                    acc[mt][nt] = __builtin_amdgcn_mfma_f32_16x16x32_bf16(ah[mt], bl, acc[mt][nt], 0,0,0);
                    acc[mt][nt] = __builtin_amdgcn_mfma_f32_16x16x32_bf16(al[mt], bh, acc[mt][nt], 0,0,0);
                }
            }
        }
    }
    __syncthreads();

    // ---------- phase 3: relu + repack into LDS for color1 ----------
    {
        const int lq = l >> 4, lr = l & 15;
#pragma unroll
        for (int mt=0; mt<4; mt++){
#pragma unroll
            for (int nt=0; nt<4; nt++){
#pragma unroll
                for (int r=0; r<4; r++){
                    float v = fmaxf(acc[mt][nt][r], 0.f);
                    uint16_t hi = f2bf(v);
                    uint16_t lo = f2bf(v - bf2f(hi));
                    int pt = mt*16 + lq*4 + r;
                    int ch = nt*16 + lr;
                    ldsA[pt*LDSH + ch] = hi;
                    ldsA[64*LDSH + pt*LDSH + ch] = lo;
                }
            }
        }
    }
    __syncthreads();

    // ---------- phase 4: color1 MFMA ----------
    {
        const int lq = l >> 4, lr = l & 15;
#pragma unroll
        for (int mt=0; mt<4; mt++)
#pragma unroll
            for (int nt=0; nt<4; nt++){
                acc[mt][nt][0]=0.f; acc[mt][nt][1]=0.f; acc[mt][nt][2]=0.f; acc[mt][nt][3]=0.f;
            }
#pragma unroll
        for (int ks=0; ks<2; ks++){
            short8v ah[4], al[4];
#pragma unroll
            for (int mt=0; mt<4; mt++){
                const uint16_t* ph = &ldsA[(mt*16+lr)*LDSH + ks*32 + lq*8];
                ah[mt] = *reinterpret_cast<const short8v*>(ph);
                al[mt] = *reinterpret_cast<const short8v*>(ph + 64*LDSH);
            }
#pragma unroll
            for (int nt=0; nt<4; nt++){
                short8v bh = *reinterpret_cast<const short8v*>(&c1Bhi[(nt*2+ks)*512 + l*8]);
                short8v bl = *reinterpret_cast<const short8v*>(&c1Blo[(nt*2+ks)*512 + l*8]);
#pragma unroll
                for (int mt=0; mt<4; mt++){
                    acc[mt][nt] = __builtin_amdgcn_mfma_f32_16x16x32_bf16(ah[mt], bh, acc[mt][nt], 0,0,0);
                    acc[mt][nt] = __builtin_amdgcn_mfma_f32_16x16x32_bf16(ah[mt], bl, acc[mt][nt], 0,0,0);
                    acc[mt][nt] = __builtin_amdgcn_mfma_f32_16x16x32_bf16(al[mt], bh, acc[mt][nt], 0,0,0);
                }
            }
        }
    }
    __syncthreads();

    // ---------- phase 5: relu -> LDS f32, color2 + sigmoid + store ----------
    {
        float* ldsF = reinterpret_cast<float*>(ldsA);   // [64][66] floats, fits in 18KB
        const int lq = l >> 4, lr = l & 15;
#pragma unroll
        for (int mt=0; mt<4; mt++){
#pragma unroll
            for (int nt=0; nt<4; nt++){
#pragma unroll
                for (int r=0; r<4; r++){
                    int pt = mt*16 + lq*4 + r;
                    int ch = nt*16 + lr;
                    ldsF[pt*66 + ch] = fmaxf(acc[mt][nt][r], 0.f);
                }
            }
        }
        __syncthreads();

        float c0=0.f, c1=0.f, c2=0.f;
        const float* row = &ldsF[l*66];
#pragma unroll
        for (int ch=0; ch<64; ch++){
            float v = row[ch];
            float4 w = ld4(&t_c2[ch*4]);
            c0 = fmaf(w.x, v, c0);
            c1 = fmaf(w.y, v, c1);
            c2 = fmaf(w.z, v, c2);
        }
        if (ok){
            float sigma = __uint_as_float(feat[(size_t)15*npts + n]);
            float4 o4;
            o4.x = 1.f/(1.f+expf(-c0));
            o4.y = 1.f/(1.f+expf(-c1));
            o4.z = 1.f/(1.f+expf(-c2));
            o4.w = sigma;
            *reinterpret_cast<float4*>(out + (size_t)n*4) = o4;
        }
    }
}

// ===================== fallback single kernel (used only if ws too small) =====================
__global__ __launch_bounds__(256, 1)
void nerf_fwd(const float* __restrict__ x,
              const float* __restrict__ hash_tables,
              const float* __restrict__ planes,
              const float* __restrict__ embed_a,
              const float* __restrict__ w_sigma0,
              const float* __restrict__ w_sigma1,
              const float* __restrict__ w_color0,
              const float* __restrict__ w_color1,
              const float* __restrict__ w_color2,
              float* __restrict__ out,
              ResArr res, int npts)
{
    __shared__ float s_ws0T[56*64];
    __shared__ float s_ws1T[64*16];
    __shared__ float s_wc0T[103*64];
    __shared__ float s_wc1T[64*64];
    __shared__ float s_wc2T[64*4];

    for (int i = threadIdx.x; i < 56*64;  i += 256){ int k=i>>6, o=i&63; s_ws0T[i] = w_sigma0[o*56+k]; }
    for (int i = threadIdx.x; i < 64*16;  i += 256){ int k=i>>4, j=i&15; s_ws1T[i] = w_sigma1[j*64+k]; }
    for (int i = threadIdx.x; i < 103*64; i += 256){ int k=i>>6, o=i&63; s_wc0T[i] = w_color0[o*103+k]; }
    for (int i = threadIdx.x; i < 64*64;  i += 256){ int k=i>>6, o=i&63; s_wc1T[i] = w_color1[o*64+k]; }
    for (int i = threadIdx.x; i < 64*4;   i += 256){ int k=i>>2, o=i&3;  s_wc2T[i] = (o<3)? w_color2[o*64+k] : 0.f; }
    __syncthreads();

    int n = blockIdx.x*256 + threadIdx.x;
    if (n >= npts) return;

    const float* xr = x + (size_t)n*7;
    float px=xr[0], py=xr[1], pz=xr[2];
    float dx=xr[3], dy=xr[4], dz=xr[5];
    float appf = xr[6];
    float p0=(px+1.f)*0.5f, p1=(py+1.f)*0.5f, p2=(pz+1.f)*0.5f;

    float acc[HID];
#pragma unroll
    for (int o=0;o<HID;o++) acc[o]=0.f;

    const float2* tabs = reinterpret_cast<const float2*>(hash_tables);
    for (int l=0; l<NLEV; l++){
        float R = res.v[l];
        float ax=p0*R, ay=p1*R, az=p2*R;
        float fx=floorf(ax), fy=floorf(ay), fz=floorf(az);
        float rx=ax-fx, ry=ay-fy, rz=az-fz;
        uint32_t ix=(uint32_t)fx, iy=(uint32_t)fy, iz=(uint32_t)fz;
        const float2* tab = tabs + (size_t)l*TSIZE;
        uint32_t hx0=ix,               hx1=ix+1u;
        uint32_t hy0=iy*2654435761u,   hy1=(iy+1u)*2654435761u;
        uint32_t hz0=iz*805459861u,    hz1=(iz+1u)*805459861u;
        float wx0=1.f-rx, wx1=rx, wy0=1.f-ry, wy1=ry, wz0=1.f-rz, wz1=rz;
        float f0=0.f, f1=0.f;
#pragma unroll
        for (int c=0;c<8;c++){
            uint32_t hxx=(c&4)?hx1:hx0;
            uint32_t hyy=(c&2)?hy1:hy0;
            uint32_t hzz=(c&1)?hz1:hz0;
            uint32_t idx=(hxx^hyy^hzz)&(TSIZE-1u);
            float2 t = tab[idx];
            float w = ((c&4)?wx1:wx0)*((c&2)?wy1:wy0)*((c&1)?wz1:wz0);
            f0 = fmaf(w,t.x,f0);
            f1 = fmaf(w,t.y,f1);
        }
        AXPY64(acc, &s_ws0T[(2*l+0)*64], f0);
        AXPY64(acc, &s_ws0T[(2*l+1)*64], f1);
    }

    float pfv[24];
    plane_enc(planes, p0, p1, p2, pfv);
#pragma unroll
    for (int j=0;j<24;j++){
        AXPY64(acc, &s_ws0T[(32+j)*64], pfv[j]);
    }

    float h1[16];
#pragma unroll
    for (int j=0;j<16;j++) h1[j]=0.f;
#pragma unroll
    for (int k=0;k<HID;k++){
        float v = fmaxf(acc[k], 0.f);
        const float* wr = &s_ws1T[k*16];
#pragma unroll
        for (int j=0;j<16;j+=4){
            float4 w=ld4(wr+j);
            h1[j+0]=fmaf(w.x,v,h1[j+0]); h1[j+1]=fmaf(w.y,v,h1[j+1]);
            h1[j+2]=fmaf(w.z,v,h1[j+2]); h1[j+3]=fmaf(w.w,v,h1[j+3]);
        }
    }
    float sg = fminf(fmaxf(h1[0], -15.f), 15.f);
    float sigma = expf(sg);

#pragma unroll
    for (int o=0;o<HID;o++) acc[o]=0.f;

    float nrm = sqrtf(dx*dx+dy*dy+dz*dz);
    float sx=dx/nrm, sy=dy/nrm, sz=dz/nrm;
    float xx=sx*sx, yy=sy*sy, zz=sz*sz, xyv=sx*sy, yzv=sy*sz, xzv=sx*sz;
    float sh[16];
    sh[0]=0.28209479177387814f;
    sh[1]=-0.48860251190291987f*sy;
    sh[2]= 0.48860251190291987f*sz;
    sh[3]=-0.48860251190291987f*sx;
    sh[4]= 1.0925484305920792f*xyv;
    sh[5]=-1.0925484305920792f*yzv;
    sh[6]= 0.94617469575756f*zz-0.31539156525252005f;
    sh[7]=-1.0925484305920792f*xzv;
    sh[8]= 0.5462742152960396f*(xx-yy);
    sh[9]=-0.5900435899266435f*sy*(3.f*xx-yy);
    sh[10]=2.890611442640554f*xyv*sz;
    sh[11]=-0.4570457994644658f*sy*(4.f*zz-xx-yy);
    sh[12]=0.3731763325901154f*sz*(2.f*zz-3.f*xx-3.f*yy);
    sh[13]=-0.4570457994644658f*sx*(4.f*zz-xx-yy);
    sh[14]=1.445305721320277f*sz*(xx-yy);
    sh[15]=-0.5900435899266435f*sx*(xx-3.f*yy);
#pragma unroll
    for (int k=0;k<16;k++){
        AXPY64(acc, &s_wc0T[k*64], sh[k]);
    }
#pragma unroll
    for (int j=0;j<15;j++){
        AXPY64(acc, &s_wc0T[(16+j)*64], h1[1+j]);
    }
    {
        int ai = (int)appf;
        const float* ar = embed_a + (size_t)ai*48;
        for (int q=0;q<12;q++){
            float4 av = ld4(ar + q*4);
            const float* wc = &s_wc0T[(31+q*4)*64];
            AXPY64(acc, wc,       av.x);
            AXPY64(acc, wc+64,    av.y);
            AXPY64(acc, wc+128,   av.z);
            AXPY64(acc, wc+192,   av.w);
        }
    }
#pragma unroll
    for (int j=0;j<24;j++){
        AXPY64(acc, &s_wc0T[(79+j)*64], pfv[j]);
    }

    float acc2[HID];
#pragma unroll
    for (int o=0;o<HID;o++) acc2[o]=0.f;
#pragma unroll
    for (int k=0;k<HID;k++){
        float v = fmaxf(acc[k], 0.f);
        AXPY64(acc2, &s_wc1T[k*64], v);
    }

    float c0a=0.f, c1a=0.f, c2a=0.f;
#pragma unroll
    for (int k=0;k<HID;k++){
        float v = fmaxf(acc2[k], 0.f);
        float4 w = ld4(&s_wc2T[k*4]);
        c0a=fmaf(w.x,v,c0a); c1a=fmaf(w.y,v,c1a); c2a=fmaf(w.z,v,c2a);
    }
    float4 o4;
    o4.x = 1.f/(1.f+expf(-c0a));
    o4.y = 1.f/(1.f+expf(-c1a));
    o4.z = 1.f/(1.f+expf(-c2a));
    o4.w = sigma;
    *reinterpret_cast<float4*>(out + (size_t)n*4) = o4;
}

extern "C" void kernel_launch(void* const* d_in, const int* in_sizes, int n_in,
                              void* d_out, int out_size, void* d_ws, size_t ws_size,
                              hipStream_t stream) {
    const float* x        = (const float*)d_in[0];
    const float* ht       = (const float*)d_in[1];
    const float* planes   = (const float*)d_in[2];
    const float* embed_a  = (const float*)d_in[3];
    const float* w_sigma0 = (const float*)d_in[4];
    const float* w_sigma1 = (const float*)d_in[5];
    const float* w_color0 = (const float*)d_in[6];
    const float* w_color1 = (const float*)d_in[7];
    const float* w_color2 = (const float*)d_in[8];
    float* out = (float*)d_out;

    int npts = in_sizes[0] / 7;

    // Replicate numpy's RES bit-exactly (same libm chain).
    ResArr res;
    double b = exp((log(2048.0) - log(16.0)) / 15.0);
    for (int l=0; l<NLEV; l++)
        res.v[l] = (float)floor(16.0 * pow(b, (double)l));

    // ws layout (bytes):
    //   t_s0: 56*64*4 = 14336
    //   t_s1: 64*16*4 =  4096
    //   t_c2: 64*4*4  =  1024
    //   a_pre: 1024*64*4 = 262144
    //   c0Bhi/c0Blo/c1Bhi/c1Blo: 4096*2 each = 8192*4 = 32768
    //   feat: npts*16*4
    const size_t OFF_S0  = 0;
    const size_t OFF_S1  = OFF_S0 + 56*64*4;
    const size_t OFF_C2  = OFF_S1 + 64*16*4;
    const size_t OFF_AP  = OFF_C2 + 64*4*4;
    const size_t OFF_B0H = OFF_AP + 1024*64*4;
    const size_t OFF_B0L = OFF_B0H + 4096*2;
    const size_t OFF_B1H = OFF_B0L + 4096*2;
    const size_t OFF_B1L = OFF_B1H + 4096*2;
    const size_t OFF_FEAT= OFF_B1L + 4096*2;   // 314368, 16B-aligned
    size_t feat_bytes = (size_t)npts * 16 * sizeof(uint32_t);

    if (ws_size >= OFF_FEAT + feat_bytes) {
        char* base = (char*)d_ws;
        float* t_s0  = (float*)(base + OFF_S0);
        float* t_s1  = (float*)(base + OFF_S1);
        float* t_c2  = (float*)(base + OFF_C2);
        float* a_pre = (float*)(base + OFF_AP);
        short* c0Bhi = (short*)(base + OFF_B0H);
        short* c0Blo = (short*)(base + OFF_B0L);
        short* c1Bhi = (short*)(base + OFF_B1H);
        short* c1Blo = (short*)(base + OFF_B1L);
        uint32_t* feat = (uint32_t*)(base + OFF_FEAT);

        hipLaunchKernelGGL(nerf_ktrans, dim3(1), dim3(256), 0, stream,
                           w_sigma0, w_sigma1, w_color0, w_color1, w_color2,
                           t_s0, t_s1, t_c2, c0Bhi, c0Blo, c1Bhi, c1Blo);
        hipLaunchKernelGGL(nerf_kpre, dim3(1024), dim3(64), 0, stream,
                           embed_a, w_color0, a_pre);

        int chunks = (npts + 511) / 512;
        hipLaunchKernelGGL(nerf_k0, dim3(8*chunks), dim3(256), 0, stream,
                           x, ht, feat, res, npts, 0);
        hipLaunchKernelGGL(nerf_k0, dim3(8*chunks), dim3(256), 0, stream,
                           x, ht, feat, res, npts, 8);

        int g = (npts + 255) / 256;
        hipLaunchKernelGGL(nerf_k1s, dim3(g), dim3(256), 0, stream,
                           x, planes, feat, t_s0, t_s1, npts);

        int gm = (npts + 63) / 64;
        hipLaunchKernelGGL(nerf_k2m, dim3(gm), dim3(64), 0, stream,
                           x, planes, feat, a_pre,
                           c0Bhi, c0Blo, c1Bhi, c1Blo, t_c2, out, npts);
    } else {
        int grid = (npts + 255) / 256;
        hipLaunchKernelGGL(nerf_fwd, dim3(grid), dim3(256), 0, stream,
                           x, ht, planes, embed_a,
                           w_sigma0, w_sigma1, w_color0, w_color1, w_color2,
                           out, res, npts);
    }
}

// Round 9
// 907.288 us; speedup vs baseline: 5.5810x; 1.1018x over previous
//
#include <hip/hip_runtime.h>
#include <cmath>
#include <stdint.h>

#define NLEV  16
#define TSIZE (1u<<19)
#define PRES  512
#define PFD   8
#define HID   64
#define LDSH  72   // short stride per point row in k2m LDS (pad for banks)

struct ResArr { float v[NLEV]; };

typedef __attribute__((ext_vector_type(8))) short short8v;   // 8 bf16 (4 VGPRs)
typedef __attribute__((ext_vector_type(4))) float f32x4;

__device__ __forceinline__ float4 ld4(const float* p){ return *reinterpret_cast<const float4*>(p); }

__device__ __forceinline__ uint16_t f2bf(float f){
    uint32_t u = __float_as_uint(f);
    uint32_t r = (u + 0x7FFFu + ((u>>16)&1u)) >> 16;
    return (uint16_t)r;
}
__device__ __forceinline__ float bf2f(uint32_t h){ return __uint_as_float(h<<16); }

// acc[o] += wT_col[o] * v (single point), static indexing
#define AXPY64(A, WPTR, V) do { const float* _w=(WPTR); const float _v=(V); \
  _Pragma("unroll") \
  for (int _o=0;_o<64;_o+=4){ float4 _w4=ld4(_w+_o); \
    A[_o+0]=fmaf(_w4.x,_v,A[_o+0]); A[_o+1]=fmaf(_w4.y,_v,A[_o+1]); \
    A[_o+2]=fmaf(_w4.z,_v,A[_o+2]); A[_o+3]=fmaf(_w4.w,_v,A[_o+3]); } } while(0)

__device__ __forceinline__ void plane_enc(const float* __restrict__ planes,
                                          float p0, float p1, float p2, float* pfv)
{
#pragma unroll
    for (int i=0;i<3;i++){
        float ua = (i==2? p1 : p0)*511.f;
        float va = (i==0? p1 : p2)*511.f;
        float uf=floorf(ua), vf=floorf(va);
        float wu=ua-uf, wv=va-vf;
        int u0=(int)uf; u0 = u0<0?0:(u0>510?510:u0);
        int v0=(int)vf; v0 = v0<0?0:(v0>510?510:v0);
        const float* pl = planes + ((size_t)i*PRES*PRES + (size_t)(u0*PRES+v0))*PFD;
        float4 a0=ld4(pl),              a1=ld4(pl+4);
        float4 b0=ld4(pl+PFD),          b1=ld4(pl+PFD+4);
        float4 c0=ld4(pl+PRES*PFD),     c1=ld4(pl+PRES*PFD+4);
        float4 d0=ld4(pl+PRES*PFD+PFD), d1=ld4(pl+PRES*PFD+PFD+4);
        float w00=(1.f-wu)*(1.f-wv), w01=(1.f-wu)*wv, w10=wu*(1.f-wv), w11=wu*wv;
        pfv[i*8+0]=a0.x*w00+b0.x*w01+c0.x*w10+d0.x*w11;
        pfv[i*8+1]=a0.y*w00+b0.y*w01+c0.y*w10+d0.y*w11;
        pfv[i*8+2]=a0.z*w00+b0.z*w01+c0.z*w10+d0.z*w11;
        pfv[i*8+3]=a0.w*w00+b0.w*w01+c0.w*w10+d0.w*w11;
        pfv[i*8+4]=a1.x*w00+b1.x*w01+c1.x*w10+d1.x*w11;
        pfv[i*8+5]=a1.y*w00+b1.y*w01+c1.y*w10+d1.y*w11;
        pfv[i*8+6]=a1.z*w00+b1.z*w01+c1.z*w10+d1.z*w11;
        pfv[i*8+7]=a1.w*w00+b1.w*w01+c1.w*w10+d1.w*w11;
    }
}

// ===================== krepack: hash tables -> bf16-packed u32 in ws =====================
__global__ void nerf_krepack(const float2* __restrict__ tabs,
                             uint32_t* __restrict__ tabs_bf, int total)
{
    int i = blockIdx.x*256 + threadIdx.x;
    if (i < total){
        float2 t = tabs[i];
        tabs_bf[i] = (uint32_t)f2bf(t.x) | ((uint32_t)f2bf(t.y)<<16);
    }
}

// ===================== kprep: pack (pos01, app) into float4 =====================
__global__ void nerf_kprep(const float* __restrict__ x, float4* __restrict__ pp, int npts)
{
    int n = blockIdx.x*256 + threadIdx.x;
    if (n < npts){
        const float* xr = x + (size_t)n*7;
        pp[n] = make_float4((xr[0]+1.f)*0.5f, (xr[1]+1.f)*0.5f, (xr[2]+1.f)*0.5f, xr[6]);
    }
}

// ===================== K0b: level-major hash gather, bf16 tables, 4 pts/thread =====================
// Launched twice (lvl_base 0/8); level = lvl_base+(bid&7) -> 1 level (2MB bf16) per XCD L2.
__global__ __launch_bounds__(256, 2)
void nerf_k0b(const float4* __restrict__ pp,
              const uint32_t* __restrict__ tabs_bf,
              uint32_t* __restrict__ feat,
              ResArr res, int npts, int lvl_base)
{
    int bid   = blockIdx.x;
    int level = lvl_base + (bid & 7);
    int chunk = bid >> 3;
    int base_n = chunk*1024 + threadIdx.x;
    float R = res.v[level];
    const uint32_t* tab = tabs_bf + (size_t)level*TSIZE;

    uint32_t g[4][8];
    float rx[4], ry[4], rz[4];
    bool ok[4];
#pragma unroll
    for (int q=0;q<4;q++){
        int n = base_n + q*256;
        ok[q] = (n < npts);
        int nc = ok[q] ? n : 0;
        float4 p = pp[nc];
        float ax=p.x*R, ay=p.y*R, az=p.z*R;
        float fx=floorf(ax), fy=floorf(ay), fz=floorf(az);
        rx[q]=ax-fx; ry[q]=ay-fy; rz[q]=az-fz;
        uint32_t ix=(uint32_t)fx, iy=(uint32_t)fy, iz=(uint32_t)fz;
        uint32_t hx0=ix,             hx1=ix+1u;
        uint32_t hy0=iy*2654435761u, hy1=(iy+1u)*2654435761u;
        uint32_t hz0=iz*805459861u,  hz1=(iz+1u)*805459861u;
#pragma unroll
        for (int c=0;c<8;c++){
            uint32_t idx = (((c&4)?hx1:hx0) ^ ((c&2)?hy1:hy0) ^ ((c&1)?hz1:hz0)) & (TSIZE-1u);
            g[q][c] = tab[idx];
        }
    }
#pragma unroll
    for (int q=0;q<4;q++){
        float wx0=1.f-rx[q], wy0=1.f-ry[q], wz0=1.f-rz[q];
        float f0=0.f, f1=0.f;
#pragma unroll
        for (int c=0;c<8;c++){
            float w = ((c&4)?rx[q]:wx0)*((c&2)?ry[q]:wy0)*((c&1)?rz[q]:wz0);
            f0 = fmaf(w, bf2f(g[q][c] & 0xFFFFu), f0);
            f1 = fmaf(w, bf2f(g[q][c] >> 16),     f1);
        }
        int n = base_n + q*256;
        if (ok[q]) feat[(size_t)level*npts + n] = (uint32_t)f2bf(f0) | ((uint32_t)f2bf(f1)<<16);
    }
}

// ===================== K0: R8 path (fp32 tables), used when ws too small for repack ====
__global__ __launch_bounds__(256, 2)
void nerf_k0(const float* __restrict__ x,
             const float* __restrict__ hash_tables,
             uint32_t* __restrict__ feat,
             ResArr res, int npts, int lvl_base)
{
    int bid   = blockIdx.x;
    int level = lvl_base + (bid & 7);
    int chunk = bid >> 3;
    int n0 = chunk*512 + threadIdx.x;
    int n1 = n0 + 256;
    float R = res.v[level];
    const float2* tab = reinterpret_cast<const float2*>(hash_tables) + (size_t)level*TSIZE;

    bool v0ok = (n0 < npts), v1ok = (n1 < npts);

    float p0a=0,p1a=0,p2a=0, p0b=0,p1b=0,p2b=0;
    if (v0ok){ const float* xr = x + (size_t)n0*7;
        p0a=(xr[0]+1.f)*0.5f; p1a=(xr[1]+1.f)*0.5f; p2a=(xr[2]+1.f)*0.5f; }
    if (v1ok){ const float* xr = x + (size_t)n1*7;
        p0b=(xr[0]+1.f)*0.5f; p1b=(xr[1]+1.f)*0.5f; p2b=(xr[2]+1.f)*0.5f; }

    float axa=p0a*R, aya=p1a*R, aza=p2a*R;
    float fxa=floorf(axa), fya=floorf(aya), fza=floorf(aza);
    float rxa=axa-fxa, rya=aya-fya, rza=aza-fza;
    uint32_t ixa=(uint32_t)fxa, iya=(uint32_t)fya, iza=(uint32_t)fza;
    uint32_t hx0a=ixa,             hx1a=ixa+1u;
    uint32_t hy0a=iya*2654435761u, hy1a=(iya+1u)*2654435761u;
    uint32_t hz0a=iza*805459861u,  hz1a=(iza+1u)*805459861u;

    float axb=p0b*R, ayb=p1b*R, azb=p2b*R;
    float fxb=floorf(axb), fyb=floorf(ayb), fzb=floorf(azb);
    float rxb=axb-fxb, ryb=ayb-fyb, rzb=azb-fzb;
    uint32_t ixb=(uint32_t)fxb, iyb=(uint32_t)fyb, izb=(uint32_t)fzb;
    uint32_t hx0b=ixb,             hx1b=ixb+1u;
    uint32_t hy0b=iyb*2654435761u, hy1b=(iyb+1u)*2654435761u;
    uint32_t hz0b=izb*805459861u,  hz1b=(izb+1u)*805459861u;

    float2 ta[8], tb[8];
#pragma unroll
    for (int c=0;c<8;c++){
        uint32_t idx = (((c&4)?hx1a:hx0a) ^ ((c&2)?hy1a:hy0a) ^ ((c&1)?hz1a:hz0a)) & (TSIZE-1u);
        ta[c] = tab[idx];
    }
#pragma unroll
    for (int c=0;c<8;c++){
        uint32_t idx = (((c&4)?hx1b:hx0b) ^ ((c&2)?hy1b:hy0b) ^ ((c&1)?hz1b:hz0b)) & (TSIZE-1u);
        tb[c] = tab[idx];
    }

    float wxa0=1.f-rxa, wya0=1.f-rya, wza0=1.f-rza;
    float f0a=0.f, f1a=0.f;
#pragma unroll
    for (int c=0;c<8;c++){
        float w = ((c&4)?rxa:wxa0)*((c&2)?rya:wya0)*((c&1)?rza:wza0);
        f0a = fmaf(w,ta[c].x,f0a); f1a = fmaf(w,ta[c].y,f1a);
    }
    float wxb0=1.f-rxb, wyb0=1.f-ryb, wzb0=1.f-rzb;
    float f0b=0.f, f1b=0.f;
#pragma unroll
    for (int c=0;c<8;c++){
        float w = ((c&4)?rxb:wxb0)*((c&2)?ryb:wyb0)*((c&1)?rzb:wzb0);
        f0b = fmaf(w,tb[c].x,f0b); f1b = fmaf(w,tb[c].y,f1b);
    }

    size_t base = (size_t)level*npts;
    if (v0ok) feat[base+n0] = (uint32_t)f2bf(f0a) | ((uint32_t)f2bf(f1a)<<16);
    if (v1ok) feat[base+n1] = (uint32_t)f2bf(f0b) | ((uint32_t)f2bf(f1b)<<16);
}

// ===================== ktrans: weight prep =====================
__global__ void nerf_ktrans(const float* __restrict__ w_sigma0,
                            const float* __restrict__ w_sigma1,
                            const float* __restrict__ w_color0,
                            const float* __restrict__ w_color1,
                            const float* __restrict__ w_color2,
                            float* __restrict__ t_s0, float* __restrict__ t_s1,
                            float* __restrict__ t_c2,
                            short* __restrict__ c0Bhi, short* __restrict__ c0Blo,
                            short* __restrict__ c1Bhi, short* __restrict__ c1Blo)
{
    int tid = threadIdx.x;
    for (int i=tid;i<56*64; i+=256){ int k=i>>6,o=i&63; t_s0[i]=w_sigma0[o*56+k]; }
    for (int i=tid;i<64*16; i+=256){ int k=i>>4,j=i&15; t_s1[i]=w_sigma1[j*64+k]; }
    for (int i=tid;i<64*4;  i+=256){ int k=i>>2,o=i&3;  t_c2[i]=(o<3)?w_color2[o*64+k]:0.f; }

    for (int idx=tid; idx<4096; idx+=256){
        int nt = idx >> 10;
        int r1 = idx & 1023;
        int ks = r1 >> 9;
        int r2 = r1 & 511;
        int l  = r2 >> 3;
        int i  = r2 & 7;
        int out = nt*16 + (l & 15);
        int kk  = ks*32 + (l >> 4)*8 + i;
        float w0 = 0.f;
        if (kk < 31)       w0 = w_color0[out*103 + kk];
        else if (kk < 55)  w0 = w_color0[out*103 + kk + 48];
        uint16_t h0 = f2bf(w0);
        uint16_t l0 = f2bf(w0 - bf2f(h0));
        c0Bhi[idx] = (short)h0; c0Blo[idx] = (short)l0;
        float w1 = w_color1[out*64 + kk];
        uint16_t h1 = f2bf(w1);
        uint16_t l1 = f2bf(w1 - bf2f(h1));
        c1Bhi[idx] = (short)h1; c1Blo[idx] = (short)l1;
    }
}

// ===================== kpre: app_pre[a][o] =====================
__global__ void nerf_kpre(const float* __restrict__ embed_a,
                          const float* __restrict__ w_color0,
                          float* __restrict__ app_pre)
{
    int a = blockIdx.x;
    int o = threadIdx.x;   // 64
    const float* er = embed_a + (size_t)a*48;
    const float* wr = w_color0 + (size_t)o*103 + 31;
    float s = 0.f;
#pragma unroll
    for (int j=0;j<48;j++) s = fmaf(er[j], wr[j], s);
    app_pre[(size_t)a*64 + o] = s;
}

// ===================== K1s: sigma MLP (R6-verified VALU path) =====================
__global__ __launch_bounds__(256, 2)
void nerf_k1s(const float* __restrict__ x,
              const float* __restrict__ planes,
              uint32_t* __restrict__ feat,
              const float* __restrict__ wT_s0,
              const float* __restrict__ wT_s1,
              int npts)
{
    int n = blockIdx.x*256 + threadIdx.x;
    if (n >= npts) return;

    uint32_t fl[NLEV];
#pragma unroll
    for (int l=0;l<NLEV;l++) fl[l] = feat[(size_t)l*npts + n];

    float acc[HID];
#pragma unroll
    for (int o=0;o<HID;o++) acc[o]=0.f;

#pragma unroll
    for (int l=0;l<NLEV;l++){
        float f0 = bf2f(fl[l] & 0xFFFFu);
        float f1 = bf2f(fl[l] >> 16);
        AXPY64(acc, &wT_s0[(2*l+0)*64], f0);
        AXPY64(acc, &wT_s0[(2*l+1)*64], f1);
    }

    const float* xr = x + (size_t)n*7;
    float p0=(xr[0]+1.f)*0.5f, p1=(xr[1]+1.f)*0.5f, p2=(xr[2]+1.f)*0.5f;
    float pfv[24];
    plane_enc(planes, p0, p1, p2, pfv);
#pragma unroll
    for (int j=0;j<24;j++){
        AXPY64(acc, &wT_s0[(32+j)*64], pfv[j]);
    }

    float h1[16];
#pragma unroll
    for (int j=0;j<16;j++) h1[j]=0.f;
#pragma unroll
    for (int k=0;k<HID;k++){
        float v = fmaxf(acc[k], 0.f);
        const float* wr = &wT_s1[k*16];
#pragma unroll
        for (int j=0;j<16;j+=4){
            float4 w=ld4(wr+j);
            h1[j+0]=fmaf(w.x,v,h1[j+0]); h1[j+1]=fmaf(w.y,v,h1[j+1]);
            h1[j+2]=fmaf(w.z,v,h1[j+2]); h1[j+3]=fmaf(w.w,v,h1[j+3]);
        }
    }
    float sg = fminf(fmaxf(h1[0], -15.f), 15.f);
    float sigma = expf(sg);

#pragma unroll
    for (int l=0;l<15;l++) feat[(size_t)l*npts + n] = __float_as_uint(h1[l+1]);
    feat[(size_t)15*npts + n] = __float_as_uint(sigma);
}

// ===================== K2m: color MLP via bf16-split MFMA (R8-verified) =====================
__global__ __launch_bounds__(64, 1)
void nerf_k2m(const float* __restrict__ x,
              const float* __restrict__ planes,
              const uint32_t* __restrict__ feat,
              const float* __restrict__ app_pre,
              const short* __restrict__ c0Bhi, const short* __restrict__ c0Blo,
              const short* __restrict__ c1Bhi, const short* __restrict__ c1Blo,
              const float* __restrict__ t_c2,
              float* __restrict__ out, int npts)
{
    __shared__ uint16_t ldsA[2*64*LDSH];
    __shared__ int      lds_ai[64];

    const int l = threadIdx.x;
    int n = blockIdx.x*64 + l;
    bool ok = (n < npts);
    int nc = ok ? n : (npts-1);
    const float* xr = x + (size_t)nc*7;

    {
        float av[55];
        float dx=xr[3], dy=xr[4], dz=xr[5];
        float nrm = sqrtf(dx*dx+dy*dy+dz*dz);
        float sx=dx/nrm, sy=dy/nrm, sz=dz/nrm;
        float xx=sx*sx, yy=sy*sy, zz=sz*sz, xyv=sx*sy, yzv=sy*sz, xzv=sx*sz;
        av[0]=0.28209479177387814f;
        av[1]=-0.48860251190291987f*sy;
        av[2]= 0.48860251190291987f*sz;
        av[3]=-0.48860251190291987f*sx;
        av[4]= 1.0925484305920792f*xyv;
        av[5]=-1.0925484305920792f*yzv;
        av[6]= 0.94617469575756f*zz-0.31539156525252005f;
        av[7]=-1.0925484305920792f*xzv;
        av[8]= 0.5462742152960396f*(xx-yy);
        av[9]=-0.5900435899266435f*sy*(3.f*xx-yy);
        av[10]=2.890611442640554f*xyv*sz;
        av[11]=-0.4570457994644658f*sy*(4.f*zz-xx-yy);
        av[12]=0.3731763325901154f*sz*(2.f*zz-3.f*xx-3.f*yy);
        av[13]=-0.4570457994644658f*sx*(4.f*zz-xx-yy);
        av[14]=1.445305721320277f*sz*(xx-yy);
        av[15]=-0.5900435899266435f*sx*(xx-3.f*yy);
#pragma unroll
        for (int j=0;j<15;j++) av[16+j] = __uint_as_float(feat[(size_t)j*npts + nc]);
        float pfv[24];
        plane_enc(planes, (xr[0]+1.f)*0.5f, (xr[1]+1.f)*0.5f, (xr[2]+1.f)*0.5f, pfv);
#pragma unroll
        for (int j=0;j<24;j++) av[31+j] = pfv[j];

        uint16_t* rh = &ldsA[l*LDSH];
        uint16_t* rl = &ldsA[64*LDSH + l*LDSH];
#pragma unroll
        for (int kk=0; kk<64; kk++){
            float a = (kk<55) ? av[kk] : 0.f;
            uint16_t hi = f2bf(a);
            uint16_t lo = f2bf(a - bf2f(hi));
            rh[kk] = hi; rl[kk] = lo;
        }
        lds_ai[l] = (int)xr[6];
    }
    __syncthreads();

    f32x4 acc[4][4];
    {
        const int lq = l >> 4, lr = l & 15;
#pragma unroll
        for (int mt=0; mt<4; mt++){
#pragma unroll
            for (int r=0; r<4; r++){
                int ai = lds_ai[mt*16 + lq*4 + r];
                const float* ap = app_pre + (size_t)ai*64 + lr;
#pragma unroll
                for (int nt=0; nt<4; nt++)
                    acc[mt][nt][r] = ap[nt*16];
            }
        }
    }
    {
        const int lq = l >> 4, lr = l & 15;
#pragma unroll
        for (int ks=0; ks<2; ks++){
            short8v ah[4], al[4];
#pragma unroll
            for (int mt=0; mt<4; mt++){
                const uint16_t* ph = &ldsA[(mt*16+lr)*LDSH + ks*32 + lq*8];
                ah[mt] = *reinterpret_cast<const short8v*>(ph);
                al[mt] = *reinterpret_cast<const short8v*>(ph + 64*LDSH);
            }
#pragma unroll
            for (int nt=0; nt<4; nt++){
                short8v bh = *reinterpret_cast<const short8v*>(&c0Bhi[(nt*2+ks)*512 + l*8]);
                short8v bl = *reinterpret_cast<const short8v*>(&c0Blo[(nt*2+ks)*512 + l*8]);
#pragma unroll
                for (int mt=0; mt<4; mt++){
                    acc[mt][nt] = __builtin_amdgcn_mfma_f32_16x16x32_bf16(ah[mt], bh, acc[mt][nt], 0,0,0);
                    acc[mt][nt] = __builtin_amdgcn_mfma_f32_16x16x32_bf16(ah[mt], bl, acc[mt][nt], 0,0,0);
                    acc[mt][nt] = __builtin_amdgcn_mfma_f32_16x16x32_bf16(al[mt], bh, acc[mt][nt], 0,0,0);
                }
            }
        }
    }
    __syncthreads();

    {
        const int lq = l >> 4, lr = l & 15;
#pragma unroll
        for (int mt=0; mt<4; mt++){
#pragma unroll
            for (int nt=0; nt<4; nt++){
#pragma unroll
                for (int r=0; r<4; r++){
                    float v = fmaxf(acc[mt][nt][r], 0.f);
                    uint16_t hi = f2bf(v);
                    uint16_t lo = f2bf(v - bf2f(hi));
                    int pt = mt*16 + lq*4 + r;
                    int ch = nt*16 + lr;
                    ldsA[pt*LDSH + ch] = hi;
                    ldsA[64*LDSH + pt*LDSH + ch] = lo;
                }
            }
        }
    }
    __syncthreads();

    {
        const int lq = l >> 4, lr = l & 15;
#pragma unroll
        for (int mt=0; mt<4; mt++)
#pragma unroll
            for (int nt=0; nt<4; nt++){
                acc[mt][nt][0]=0.f; acc[mt][nt][1]=0.f; acc[mt][nt][2]=0.f; acc[mt][nt][3]=0.f;
            }
#pragma unroll
        for (int ks=0; ks<2; ks++){
            short8v ah[4], al[4];
#pragma unroll
            for (int mt=0; mt<4; mt++){
                const uint16_t* ph = &ldsA[(mt*16+lr)*LDSH + ks*32 + lq*8];
                ah[mt] = *reinterpret_cast<const short8v*>(ph);
                al[mt] = *reinterpret_cast<const short8v*>(ph + 64*LDSH);
            }
#pragma unroll
            for (int nt=0; nt<4; nt++){
                short8v bh = *reinterpret_cast<const short8v*>(&c1Bhi[(nt*2+ks)*512 + l*8]);
                short8v bl = *reinterpret_cast<const short8v*>(&c1Blo[(nt*2+ks)*512 + l*8]);
#pragma unroll
                for (int mt=0; mt<4; mt++){
                    acc[mt][nt] = __builtin_amdgcn_mfma_f32_16x16x32_bf16(ah[mt], bh, acc[mt][nt], 0,0,0);
                    acc[mt][nt] = __builtin_amdgcn_mfma_f32_16x16x32_bf16(ah[mt], bl, acc[mt][nt], 0,0,0);
                    acc[mt][nt] = __builtin_amdgcn_mfma_f32_16x16x32_bf16(al[mt], bh, acc[mt][nt], 0,0,0);
                }
            }
        }
    }
    __syncthreads();

    {
        float* ldsF = reinterpret_cast<float*>(ldsA);
        const int lq = l >> 4, lr = l & 15;
#pragma unroll
        for (int mt=0; mt<4; mt++){
#pragma unroll
            for (int nt=0; nt<4; nt++){
#pragma unroll
                for (int r=0; r<4; r++){
                    int pt = mt*16 + lq*4 + r;
                    int ch = nt*16 + lr;
                    ldsF[pt*66 + ch] = fmaxf(acc[mt][nt][r], 0.f);
                }
            }
        }
        __syncthreads();

        float c0=0.f, c1=0.f, c2=0.f;
        const float* row = &ldsF[l*66];
#pragma unroll
        for (int ch=0; ch<64; ch++){
            float v = row[ch];
            float4 w = ld4(&t_c2[ch*4]);
            c0 = fmaf(w.x, v, c0);
            c1 = fmaf(w.y, v, c1);
            c2 = fmaf(w.z, v, c2);
        }
        if (ok){
            float sigma = __uint_as_float(feat[(size_t)15*npts + n]);
            float4 o4;
            o4.x = 1.f/(1.f+expf(-c0));
            o4.y = 1.f/(1.f+expf(-c1));
            o4.z = 1.f/(1.f+expf(-c2));
            o4.w = sigma;
            *reinterpret_cast<float4*>(out + (size_t)n*4) = o4;
        }
    }
}

// ===================== fallback single kernel (used only if ws too small) =====================
__global__ __launch_bounds__(256, 1)
void nerf_fwd(const float* __restrict__ x,
              const float* __restrict__ hash_tables,
              const float* __restrict__ planes,
              const float* __restrict__ embed_a,
              const float* __restrict__ w_sigma0,
              const float* __restrict__ w_sigma1,
              const float* __restrict__ w_color0,
              const float* __restrict__ w_color1,
              const float* __restrict__ w_color2,
              float* __restrict__ out,
              ResArr res, int npts)
{
    __shared__ float s_ws0T[56*64];
    __shared__ float s_ws1T[64*16];
    __shared__ float s_wc0T[103*64];
    __shared__ float s_wc1T[64*64];
    __shared__ float s_wc2T[64*4];

    for (int i = threadIdx.x; i < 56*64;  i += 256){ int k=i>>6, o=i&63; s_ws0T[i] = w_sigma0[o*56+k]; }
    for (int i = threadIdx.x; i < 64*16;  i += 256){ int k=i>>4, j=i&15; s_ws1T[i] = w_sigma1[j*64+k]; }
    for (int i = threadIdx.x; i < 103*64; i += 256){ int k=i>>6, o=i&63; s_wc0T[i] = w_color0[o*103+k]; }
    for (int i = threadIdx.x; i < 64*64;  i += 256){ int k=i>>6, o=i&63; s_wc1T[i] = w_color1[o*64+k]; }
    for (int i = threadIdx.x; i < 64*4;   i += 256){ int k=i>>2, o=i&3;  s_wc2T[i] = (o<3)? w_color2[o*64+k] : 0.f; }
    __syncthreads();

    int n = blockIdx.x*256 + threadIdx.x;
    if (n >= npts) return;

    const float* xr = x + (size_t)n*7;
    float px=xr[0], py=xr[1], pz=xr[2];
    float dx=xr[3], dy=xr[4], dz=xr[5];
    float appf = xr[6];
    float p0=(px+1.f)*0.5f, p1=(py+1.f)*0.5f, p2=(pz+1.f)*0.5f;

    float acc[HID];
#pragma unroll
    for (int o=0;o<HID;o++) acc[o]=0.f;

    const float2* tabs = reinterpret_cast<const float2*>(hash_tables);
    for (int l=0; l<NLEV; l++){
        float R = res.v[l];
        float ax=p0*R, ay=p1*R, az=p2*R;
        float fx=floorf(ax), fy=floorf(ay), fz=floorf(az);
        float rx=ax-fx, ry=ay-fy, rz=az-fz;
        uint32_t ix=(uint32_t)fx, iy=(uint32_t)fy, iz=(uint32_t)fz;
        const float2* tab = tabs + (size_t)l*TSIZE;
        uint32_t hx0=ix,               hx1=ix+1u;
        uint32_t hy0=iy*2654435761u,   hy1=(iy+1u)*2654435761u;
        uint32_t hz0=iz*805459861u,    hz1=(iz+1u)*805459861u;
        float wx0=1.f-rx, wx1=rx, wy0=1.f-ry, wy1=ry, wz0=1.f-rz, wz1=rz;
        float f0=0.f, f1=0.f;
#pragma unroll
        for (int c=0;c<8;c++){
            uint32_t hxx=(c&4)?hx1:hx0;
            uint32_t hyy=(c&2)?hy1:hy0;
            uint32_t hzz=(c&1)?hz1:hz0;
            uint32_t idx=(hxx^hyy^hzz)&(TSIZE-1u);
            float2 t = tab[idx];
            float w = ((c&4)?wx1:wx0)*((c&2)?wy1:wy0)*((c&1)?wz1:wz0);
            f0 = fmaf(w,t.x,f0);
            f1 = fmaf(w,t.y,f1);
        }
        AXPY64(acc, &s_ws0T[(2*l+0)*64], f0);
        AXPY64(acc, &s_ws0T[(2*l+1)*64], f1);
    }

    float pfv[24];
    plane_enc(planes, p0, p1, p2, pfv);
#pragma unroll
    for (int j=0;j<24;j++){
        AXPY64(acc, &s_ws0T[(32+j)*64], pfv[j]);
    }

    float h1[16];
#pragma unroll
    for (int j=0;j<16;j++) h1[j]=0.f;
#pragma unroll
    for (int k=0;k<HID;k++){
        float v = fmaxf(acc[k], 0.f);
        const float* wr = &s_ws1T[k*16];
#pragma unroll
        for (int j=0;j<16;j+=4){
            float4 w=ld4(wr+j);
            h1[j+0]=fmaf(w.x,v,h1[j+0]); h1[j+1]=fmaf(w.y,v,h1[j+1]);
            h1[j+2]=fmaf(w.z,v,h1[j+2]); h1[j+3]=fmaf(w.w,v,h1[j+3]);
        }
    }
    float sg = fminf(fmaxf(h1[0], -15.f), 15.f);
    float sigma = expf(sg);

#pragma unroll
    for (int o=0;o<HID;o++) acc[o]=0.f;

    float nrm = sqrtf(dx*dx+dy*dy+dz*dz);
    float sx=dx/nrm, sy=dy/nrm, sz=dz/nrm;
    float xx=sx*sx, yy=sy*sy, zz=sz*sz, xyv=sx*sy, yzv=sy*sz, xzv=sx*sz;
    float sh[16];
    sh[0]=0.28209479177387814f;
    sh[1]=-0.48860251190291987f*sy;
    sh[2]= 0.48860251190291987f*sz;
    sh[3]=-0.48860251190291987f*sx;
    sh[4]= 1.0925484305920792f*xyv;
    sh[5]=-1.0925484305920792f*yzv;
    sh[6]= 0.94617469575756f*zz-0.31539156525252005f;
    sh[7]=-1.0925484305920792f*xzv;
    sh[8]= 0.5462742152960396f*(xx-yy);
    sh[9]=-0.5900435899266435f*sy*(3.f*xx-yy);
    sh[10]=2.890611442640554f*xyv*sz;
    sh[11]=-0.4570457994644658f*sy*(4.f*zz-xx-yy);
    sh[12]=0.3731763325901154f*sz*(2.f*zz-3.f*xx-3.f*yy);
    sh[13]=-0.4570457994644658f*sx*(4.f*zz-xx-yy);
    sh[14]=1.445305721320277f*sz*(xx-yy);
    sh[15]=-0.5900435899266435f*sx*(xx-3.f*yy);
#pragma unroll
    for (int k=0;k<16;k++){
        AXPY64(acc, &s_wc0T[k*64], sh[k]);
    }
#pragma unroll
    for (int j=0;j<15;j++){
        AXPY64(acc, &s_wc0T[(16+j)*64], h1[1+j]);
    }
    {
        int ai = (int)appf;
        const float* ar = embed_a + (size_t)ai*48;
        for (int q=0;q<12;q++){
            float4 av = ld4(ar + q*4);
            const float* wc = &s_wc0T[(31+q*4)*64];
            AXPY64(acc, wc,       av.x);
            AXPY64(acc, wc+64,    av.y);
            AXPY64(acc, wc+128,   av.z);
            AXPY64(acc, wc+192,   av.w);
        }
    }
#pragma unroll
    for (int j=0;j<24;j++){
        AXPY64(acc, &s_wc0T[(79+j)*64], pfv[j]);
    }

    float acc2[HID];
#pragma unroll
    for (int o=0;o<HID;o++) acc2[o]=0.f;
#pragma unroll
    for (int k=0;k<HID;k++){
        float v = fmaxf(acc[k], 0.f);
        AXPY64(acc2, &s_wc1T[k*64], v);
    }

    float c0a=0.f, c1a=0.f, c2a=0.f;
#pragma unroll
    for (int k=0;k<HID;k++){
        float v = fmaxf(acc2[k], 0.f);
        float4 w = ld4(&s_wc2T[k*4]);
        c0a=fmaf(w.x,v,c0a); c1a=fmaf(w.y,v,c1a); c2a=fmaf(w.z,v,c2a);
    }
    float4 o4;
    o4.x = 1.f/(1.f+expf(-c0a));
    o4.y = 1.f/(1.f+expf(-c1a));
    o4.z = 1.f/(1.f+expf(-c2a));
    o4.w = sigma;
    *reinterpret_cast<float4*>(out + (size_t)n*4) = o4;
}

extern "C" void kernel_launch(void* const* d_in, const int* in_sizes, int n_in,
                              void* d_out, int out_size, void* d_ws, size_t ws_size,
                              hipStream_t stream) {
    const float* x        = (const float*)d_in[0];
    const float* ht       = (const float*)d_in[1];
    const float* planes   = (const float*)d_in[2];
    const float* embed_a  = (const float*)d_in[3];
    const float* w_sigma0 = (const float*)d_in[4];
    const float* w_sigma1 = (const float*)d_in[5];
    const float* w_color0 = (const float*)d_in[6];
    const float* w_color1 = (const float*)d_in[7];
    const float* w_color2 = (const float*)d_in[8];
    float* out = (float*)d_out;

    int npts = in_sizes[0] / 7;

    // Replicate numpy's RES bit-exactly (same libm chain).
    ResArr res;
    double b = exp((log(2048.0) - log(16.0)) / 15.0);
    for (int l=0; l<NLEV; l++)
        res.v[l] = (float)floor(16.0 * pow(b, (double)l));

    // ws layout (bytes):
    //   small block (R8): t_s0,t_s1,t_c2,a_pre,B-frags = 314368
    //   then: pp (npts*16) | tabs_bf (16*TSIZE*4 = 32MB) | feat (npts*16*4)
    const size_t OFF_S0  = 0;
    const size_t OFF_S1  = OFF_S0 + 56*64*4;
    const size_t OFF_C2  = OFF_S1 + 64*16*4;
    const size_t OFF_AP  = OFF_C2 + 64*4*4;
    const size_t OFF_B0H = OFF_AP + 1024*64*4;
    const size_t OFF_B0L = OFF_B0H + 4096*2;
    const size_t OFF_B1H = OFF_B0L + 4096*2;
    const size_t OFF_B1L = OFF_B1H + 4096*2;
    const size_t OFF_SMALL_END = OFF_B1L + 4096*2;   // 314368, 16B-aligned
    size_t feat_bytes = (size_t)npts * 16 * sizeof(uint32_t);
    size_t pp_bytes   = (size_t)npts * 16;
    size_t tb_bytes   = (size_t)16 * TSIZE * 4;      // 32MB

    const size_t OFF_PP   = OFF_SMALL_END;
    const size_t OFF_TB   = OFF_PP + pp_bytes;
    const size_t OFF_FEAT2= OFF_TB + tb_bytes;
    const size_t OFF_FEAT1= OFF_SMALL_END;           // R8 path: feat right after small

    bool full_path = (ws_size >= OFF_FEAT2 + feat_bytes);
    bool mid_path  = (ws_size >= OFF_FEAT1 + feat_bytes);

    if (full_path || mid_path) {
        char* base = (char*)d_ws;
        float* t_s0  = (float*)(base + OFF_S0);
        float* t_s1  = (float*)(base + OFF_S1);
        float* t_c2  = (float*)(base + OFF_C2);
        float* a_pre = (float*)(base + OFF_AP);
        short* c0Bhi = (short*)(base + OFF_B0H);
        short* c0Blo = (short*)(base + OFF_B0L);
        short* c1Bhi = (short*)(base + OFF_B1H);
        short* c1Blo = (short*)(base + OFF_B1L);

        hipLaunchKernelGGL(nerf_ktrans, dim3(1), dim3(256), 0, stream,
                           w_sigma0, w_sigma1, w_color0, w_color1, w_color2,
                           t_s0, t_s1, t_c2, c0Bhi, c0Blo, c1Bhi, c1Blo);
        hipLaunchKernelGGL(nerf_kpre, dim3(1024), dim3(64), 0, stream,
                           embed_a, w_color0, a_pre);

        uint32_t* feat;
        if (full_path) {
            float4*   pp      = (float4*)(base + OFF_PP);
            uint32_t* tabs_bf = (uint32_t*)(base + OFF_TB);
            feat              = (uint32_t*)(base + OFF_FEAT2);

            int total = 16 * (int)TSIZE;
            hipLaunchKernelGGL(nerf_krepack, dim3((total+255)/256), dim3(256), 0, stream,
                               (const float2*)ht, tabs_bf, total);
            hipLaunchKernelGGL(nerf_kprep, dim3((npts+255)/256), dim3(256), 0, stream,
                               x, pp, npts);

            int chunks = (npts + 1023) / 1024;
            hipLaunchKernelGGL(nerf_k0b, dim3(8*chunks), dim3(256), 0, stream,
                               pp, tabs_bf, feat, res, npts, 0);
            hipLaunchKernelGGL(nerf_k0b, dim3(8*chunks), dim3(256), 0, stream,
                               pp, tabs_bf, feat, res, npts, 8);
        } else {
            feat = (uint32_t*)(base + OFF_FEAT1);
            int chunks = (npts + 511) / 512;
            hipLaunchKernelGGL(nerf_k0, dim3(8*chunks), dim3(256), 0, stream,
                               x, ht, feat, res, npts, 0);
            hipLaunchKernelGGL(nerf_k0, dim3(8*chunks), dim3(256), 0, stream,
                               x, ht, feat, res, npts, 8);
        }

        int g = (npts + 255) / 256;
        hipLaunchKernelGGL(nerf_k1s, dim3(g), dim3(256), 0, stream,
                           x, planes, feat, t_s0, t_s1, npts);

        int gm = (npts + 63) / 64;
        hipLaunchKernelGGL(nerf_k2m, dim3(gm), dim3(64), 0, stream,
                           x, planes, feat, a_pre,
                           c0Bhi, c0Blo, c1Bhi, c1Blo, t_c2, out, npts);
    } else {
        int grid = (npts + 255) / 256;
        hipLaunchKernelGGL(nerf_fwd, dim3(grid), dim3(256), 0, stream,
                           x, ht, planes, embed_a,
                           w_sigma0, w_sigma1, w_color0, w_color1, w_color2,
                           out, res, npts);
    }
}

// Round 10
// 711.247 us; speedup vs baseline: 7.1193x; 1.2756x over previous
//
#include <hip/hip_runtime.h>
#include <cmath>
#include <stdint.h>

#define NLEV  16
#define TSIZE (1u<<19)
#define PRES  512
#define PFD   8
#define HID   64
#define LDSH  72   // short stride per point row in MFMA LDS (pad for banks)

struct ResArr { float v[NLEV]; };

typedef __attribute__((ext_vector_type(8))) short short8v;   // 8 bf16 (4 VGPRs)
typedef __attribute__((ext_vector_type(4))) float f32x4;

__device__ __forceinline__ float4 ld4(const float* p){ return *reinterpret_cast<const float4*>(p); }

__device__ __forceinline__ uint16_t f2bf(float f){
    uint32_t u = __float_as_uint(f);
    uint32_t r = (u + 0x7FFFu + ((u>>16)&1u)) >> 16;
    return (uint16_t)r;
}
__device__ __forceinline__ float bf2f(uint32_t h){ return __uint_as_float(h<<16); }

#define AXPY64(A, WPTR, V) do { const float* _w=(WPTR); const float _v=(V); \
  _Pragma("unroll") \
  for (int _o=0;_o<64;_o+=4){ float4 _w4=ld4(_w+_o); \
    A[_o+0]=fmaf(_w4.x,_v,A[_o+0]); A[_o+1]=fmaf(_w4.y,_v,A[_o+1]); \
    A[_o+2]=fmaf(_w4.z,_v,A[_o+2]); A[_o+3]=fmaf(_w4.w,_v,A[_o+3]); } } while(0)

__device__ __forceinline__ void plane_enc(const float* __restrict__ planes,
                                          float p0, float p1, float p2, float* pfv)
{
#pragma unroll
    for (int i=0;i<3;i++){
        float ua = (i==2? p1 : p0)*511.f;
        float va = (i==0? p1 : p2)*511.f;
        float uf=floorf(ua), vf=floorf(va);
        float wu=ua-uf, wv=va-vf;
        int u0=(int)uf; u0 = u0<0?0:(u0>510?510:u0);
        int v0=(int)vf; v0 = v0<0?0:(v0>510?510:v0);
        const float* pl = planes + ((size_t)i*PRES*PRES + (size_t)(u0*PRES+v0))*PFD;
        float4 a0=ld4(pl),              a1=ld4(pl+4);
        float4 b0=ld4(pl+PFD),          b1=ld4(pl+PFD+4);
        float4 c0=ld4(pl+PRES*PFD),     c1=ld4(pl+PRES*PFD+4);
        float4 d0=ld4(pl+PRES*PFD+PFD), d1=ld4(pl+PRES*PFD+PFD+4);
        float w00=(1.f-wu)*(1.f-wv), w01=(1.f-wu)*wv, w10=wu*(1.f-wv), w11=wu*wv;
        pfv[i*8+0]=a0.x*w00+b0.x*w01+c0.x*w10+d0.x*w11;
        pfv[i*8+1]=a0.y*w00+b0.y*w01+c0.y*w10+d0.y*w11;
        pfv[i*8+2]=a0.z*w00+b0.z*w01+c0.z*w10+d0.z*w11;
        pfv[i*8+3]=a0.w*w00+b0.w*w01+c0.w*w10+d0.w*w11;
        pfv[i*8+4]=a1.x*w00+b1.x*w01+c1.x*w10+d1.x*w11;
        pfv[i*8+5]=a1.y*w00+b1.y*w01+c1.y*w10+d1.y*w11;
        pfv[i*8+6]=a1.z*w00+b1.z*w01+c1.z*w10+d1.z*w11;
        pfv[i*8+7]=a1.w*w00+b1.w*w01+c1.w*w10+d1.w*w11;
    }
}

// ===================== krepack: hash tables -> bf16-packed u32 =====================
__global__ void nerf_krepack(const float2* __restrict__ tabs,
                             uint32_t* __restrict__ tabs_bf, int total)
{
    int i = blockIdx.x*256 + threadIdx.x;
    if (i < total){
        float2 t = tabs[i];
        tabs_bf[i] = (uint32_t)f2bf(t.x) | ((uint32_t)f2bf(t.y)<<16);
    }
}

// ===================== kprep: pack (pos01, app) into float4 =====================
__global__ void nerf_kprep(const float* __restrict__ x, float4* __restrict__ pp, int npts)
{
    int n = blockIdx.x*256 + threadIdx.x;
    if (n < npts){
        const float* xr = x + (size_t)n*7;
        pp[n] = make_float4((xr[0]+1.f)*0.5f, (xr[1]+1.f)*0.5f, (xr[2]+1.f)*0.5f, xr[6]);
    }
}

// ===================== K0b: level-major hash gather, bf16 tables, 4 pts/thread ====
__global__ __launch_bounds__(256, 2)
void nerf_k0b(const float4* __restrict__ pp,
              const uint32_t* __restrict__ tabs_bf,
              uint32_t* __restrict__ feat,
              ResArr res, int npts, int lvl_base)
{
    int bid   = blockIdx.x;
    int level = lvl_base + (bid & 7);
    int chunk = bid >> 3;
    int base_n = chunk*1024 + threadIdx.x;
    float R = res.v[level];
    const uint32_t* tab = tabs_bf + (size_t)level*TSIZE;

    uint32_t g[4][8];
    float rx[4], ry[4], rz[4];
    bool ok[4];
#pragma unroll
    for (int q=0;q<4;q++){
        int n = base_n + q*256;
        ok[q] = (n < npts);
        int nc = ok[q] ? n : 0;
        float4 p = pp[nc];
        float ax=p.x*R, ay=p.y*R, az=p.z*R;
        float fx=floorf(ax), fy=floorf(ay), fz=floorf(az);
        rx[q]=ax-fx; ry[q]=ay-fy; rz[q]=az-fz;
        uint32_t ix=(uint32_t)fx, iy=(uint32_t)fy, iz=(uint32_t)fz;
        uint32_t hx0=ix,             hx1=ix+1u;
        uint32_t hy0=iy*2654435761u, hy1=(iy+1u)*2654435761u;
        uint32_t hz0=iz*805459861u,  hz1=(iz+1u)*805459861u;
#pragma unroll
        for (int c=0;c<8;c++){
            uint32_t idx = (((c&4)?hx1:hx0) ^ ((c&2)?hy1:hy0) ^ ((c&1)?hz1:hz0)) & (TSIZE-1u);
            g[q][c] = tab[idx];
        }
    }
#pragma unroll
    for (int q=0;q<4;q++){
        float wx0=1.f-rx[q], wy0=1.f-ry[q], wz0=1.f-rz[q];
        float f0=0.f, f1=0.f;
#pragma unroll
        for (int c=0;c<8;c++){
            float w = ((c&4)?rx[q]:wx0)*((c&2)?ry[q]:wy0)*((c&1)?rz[q]:wz0);
            f0 = fmaf(w, bf2f(g[q][c] & 0xFFFFu), f0);
            f1 = fmaf(w, bf2f(g[q][c] >> 16),     f1);
        }
        int n = base_n + q*256;
        if (ok[q]) feat[(size_t)level*npts + n] = (uint32_t)f2bf(f0) | ((uint32_t)f2bf(f1)<<16);
    }
}

// ===================== K0: mid path (fp32 tables) =====================
__global__ __launch_bounds__(256, 2)
void nerf_k0(const float* __restrict__ x,
             const float* __restrict__ hash_tables,
             uint32_t* __restrict__ feat,
             ResArr res, int npts, int lvl_base)
{
    int bid   = blockIdx.x;
    int level = lvl_base + (bid & 7);
    int chunk = bid >> 3;
    int n0 = chunk*512 + threadIdx.x;
    int n1 = n0 + 256;
    float R = res.v[level];
    const float2* tab = reinterpret_cast<const float2*>(hash_tables) + (size_t)level*TSIZE;

    bool v0ok = (n0 < npts), v1ok = (n1 < npts);

    float p0a=0,p1a=0,p2a=0, p0b=0,p1b=0,p2b=0;
    if (v0ok){ const float* xr = x + (size_t)n0*7;
        p0a=(xr[0]+1.f)*0.5f; p1a=(xr[1]+1.f)*0.5f; p2a=(xr[2]+1.f)*0.5f; }
    if (v1ok){ const float* xr = x + (size_t)n1*7;
        p0b=(xr[0]+1.f)*0.5f; p1b=(xr[1]+1.f)*0.5f; p2b=(xr[2]+1.f)*0.5f; }

    float axa=p0a*R, aya=p1a*R, aza=p2a*R;
    float fxa=floorf(axa), fya=floorf(aya), fza=floorf(aza);
    float rxa=axa-fxa, rya=aya-fya, rza=aza-fza;
    uint32_t ixa=(uint32_t)fxa, iya=(uint32_t)fya, iza=(uint32_t)fza;
    uint32_t hx0a=ixa,             hx1a=ixa+1u;
    uint32_t hy0a=iya*2654435761u, hy1a=(iya+1u)*2654435761u;
    uint32_t hz0a=iza*805459861u,  hz1a=(iza+1u)*805459861u;

    float axb=p0b*R, ayb=p1b*R, azb=p2b*R;
    float fxb=floorf(axb), fyb=floorf(ayb), fzb=floorf(azb);
    float rxb=axb-fxb, ryb=ayb-fyb, rzb=azb-fzb;
    uint32_t ixb=(uint32_t)fxb, iyb=(uint32_t)fyb, izb=(uint32_t)fzb;
    uint32_t hx0b=ixb,             hx1b=ixb+1u;
    uint32_t hy0b=iyb*2654435761u, hy1b=(iyb+1u)*2654435761u;
    uint32_t hz0b=izb*805459861u,  hz1b=(izb+1u)*805459861u;

    float2 ta[8], tb[8];
#pragma unroll
    for (int c=0;c<8;c++){
        uint32_t idx = (((c&4)?hx1a:hx0a) ^ ((c&2)?hy1a:hy0a) ^ ((c&1)?hz1a:hz0a)) & (TSIZE-1u);
        ta[c] = tab[idx];
    }
#pragma unroll
    for (int c=0;c<8;c++){
        uint32_t idx = (((c&4)?hx1b:hx0b) ^ ((c&2)?hy1b:hy0b) ^ ((c&1)?hz1b:hz0b)) & (TSIZE-1u);
        tb[c] = tab[idx];
    }

    float wxa0=1.f-rxa, wya0=1.f-rya, wza0=1.f-rza;
    float f0a=0.f, f1a=0.f;
#pragma unroll
    for (int c=0;c<8;c++){
        float w = ((c&4)?rxa:wxa0)*((c&2)?rya:wya0)*((c&1)?rza:wza0);
        f0a = fmaf(w,ta[c].x,f0a); f1a = fmaf(w,ta[c].y,f1a);
    }
    float wxb0=1.f-rxb, wyb0=1.f-ryb, wzb0=1.f-rzb;
    float f0b=0.f, f1b=0.f;
#pragma unroll
    for (int c=0;c<8;c++){
        float w = ((c&4)?rxb:wxb0)*((c&2)?ryb:wyb0)*((c&1)?rzb:wzb0);
        f0b = fmaf(w,tb[c].x,f0b); f1b = fmaf(w,tb[c].y,f1b);
    }

    size_t base = (size_t)level*npts;
    if (v0ok) feat[base+n0] = (uint32_t)f2bf(f0a) | ((uint32_t)f2bf(f1a)<<16);
    if (v1ok) feat[base+n1] = (uint32_t)f2bf(f0b) | ((uint32_t)f2bf(f1b)<<16);
}

// ===================== ktrans: weight prep =====================
// B-fragment layout (all MFMA matrices): idx = nt*1024 + ks*512 + l*8 + i
//   value = w[out = nt*16+(l&15)][k = ks*32+(l>>4)*8+i]
__global__ void nerf_ktrans(const float* __restrict__ w_sigma0,
                            const float* __restrict__ w_sigma1,
                            const float* __restrict__ w_color0,
                            const float* __restrict__ w_color1,
                            const float* __restrict__ w_color2,
                            float* __restrict__ t_s0, float* __restrict__ t_s1,
                            float* __restrict__ t_c2,
                            short* __restrict__ c0Bhi, short* __restrict__ c0Blo,
                            short* __restrict__ c1Bhi, short* __restrict__ c1Blo,
                            short* __restrict__ s0Bhi, short* __restrict__ s0Blo,
                            short* __restrict__ s1Bhi, short* __restrict__ s1Blo)
{
    int tid = threadIdx.x;
    for (int i=tid;i<56*64; i+=256){ int k=i>>6,o=i&63; t_s0[i]=w_sigma0[o*56+k]; }
    for (int i=tid;i<64*16; i+=256){ int k=i>>4,j=i&15; t_s1[i]=w_sigma1[j*64+k]; }
    for (int i=tid;i<64*4;  i+=256){ int k=i>>2,o=i&3;  t_c2[i]=(o<3)?w_color2[o*64+k]:0.f; }

    for (int idx=tid; idx<4096; idx+=256){
        int nt = idx >> 10;
        int r1 = idx & 1023;
        int ks = r1 >> 9;
        int r2 = r1 & 511;
        int l  = r2 >> 3;
        int i  = r2 & 7;
        int out = nt*16 + (l & 15);
        int kk  = ks*32 + (l >> 4)*8 + i;
        // color0: cols 0..30 = sh+geo, 31..54 = pf (w cols +48), pad 0
        float w0 = 0.f;
        if (kk < 31)       w0 = w_color0[out*103 + kk];
        else if (kk < 55)  w0 = w_color0[out*103 + kk + 48];
        uint16_t h0 = f2bf(w0);
        uint16_t l0 = f2bf(w0 - bf2f(h0));
        c0Bhi[idx] = (short)h0; c0Blo[idx] = (short)l0;
        // color1: K=64 direct
        float w1 = w_color1[out*64 + kk];
        uint16_t h1 = f2bf(w1);
        uint16_t l1 = f2bf(w1 - bf2f(h1));
        c1Bhi[idx] = (short)h1; c1Blo[idx] = (short)l1;
        // sigma0: cols 0..31 hash, 32..55 planes, pad 0
        float ws = (kk < 56) ? w_sigma0[out*56 + kk] : 0.f;
        uint16_t hs = f2bf(ws);
        uint16_t ls = f2bf(ws - bf2f(hs));
        s0Bhi[idx] = (short)hs; s0Blo[idx] = (short)ls;
    }
    // sigma1: out=16 (1 nt tile), idx = ks*512 + l*8 + i
    for (int idx=tid; idx<1024; idx+=256){
        int ks = idx >> 9;
        int r2 = idx & 511;
        int l  = r2 >> 3;
        int i  = r2 & 7;
        int out = l & 15;
        int kk  = ks*32 + (l >> 4)*8 + i;
        float w = w_sigma1[out*64 + kk];
        uint16_t h = f2bf(w);
        uint16_t lo = f2bf(w - bf2f(h));
        s1Bhi[idx] = (short)h; s1Blo[idx] = (short)lo;
    }
}

// ===================== kpre: app_pre[a][o] =====================
__global__ void nerf_kpre(const float* __restrict__ embed_a,
                          const float* __restrict__ w_color0,
                          float* __restrict__ app_pre)
{
    int a = blockIdx.x;
    int o = threadIdx.x;   // 64
    const float* er = embed_a + (size_t)a*48;
    const float* wr = w_color0 + (size_t)o*103 + 31;
    float s = 0.f;
#pragma unroll
    for (int j=0;j<48;j++) s = fmaf(er[j], wr[j], s);
    app_pre[(size_t)a*64 + o] = s;
}

// ===================== K1s: mid-path sigma MLP (VALU) =====================
__global__ __launch_bounds__(256, 2)
void nerf_k1s(const float* __restrict__ x,
              const float* __restrict__ planes,
              uint32_t* __restrict__ feat,
              const float* __restrict__ wT_s0,
              const float* __restrict__ wT_s1,
              int npts)
{
    int n = blockIdx.x*256 + threadIdx.x;
    if (n >= npts) return;

    uint32_t fl[NLEV];
#pragma unroll
    for (int l=0;l<NLEV;l++) fl[l] = feat[(size_t)l*npts + n];

    float acc[HID];
#pragma unroll
    for (int o=0;o<HID;o++) acc[o]=0.f;

#pragma unroll
    for (int l=0;l<NLEV;l++){
        float f0 = bf2f(fl[l] & 0xFFFFu);
        float f1 = bf2f(fl[l] >> 16);
        AXPY64(acc, &wT_s0[(2*l+0)*64], f0);
        AXPY64(acc, &wT_s0[(2*l+1)*64], f1);
    }

    const float* xr = x + (size_t)n*7;
    float p0=(xr[0]+1.f)*0.5f, p1=(xr[1]+1.f)*0.5f, p2=(xr[2]+1.f)*0.5f;
    float pfv[24];
    plane_enc(planes, p0, p1, p2, pfv);
#pragma unroll
    for (int j=0;j<24;j++){
        AXPY64(acc, &wT_s0[(32+j)*64], pfv[j]);
    }

    float h1[16];
#pragma unroll
    for (int j=0;j<16;j++) h1[j]=0.f;
#pragma unroll
    for (int k=0;k<HID;k++){
        float v = fmaxf(acc[k], 0.f);
        const float* wr = &wT_s1[k*16];
#pragma unroll
        for (int j=0;j<16;j+=4){
            float4 w=ld4(wr+j);
            h1[j+0]=fmaf(w.x,v,h1[j+0]); h1[j+1]=fmaf(w.y,v,h1[j+1]);
            h1[j+2]=fmaf(w.z,v,h1[j+2]); h1[j+3]=fmaf(w.w,v,h1[j+3]);
        }
    }
    float sg = fminf(fmaxf(h1[0], -15.f), 15.f);
    float sigma = expf(sg);

#pragma unroll
    for (int l=0;l<15;l++) feat[(size_t)l*npts + n] = __float_as_uint(h1[l+1]);
    feat[(size_t)15*npts + n] = __float_as_uint(sigma);
}

// ===================== K2m: mid-path color MLP (MFMA, R8-verified) =====================
__global__ __launch_bounds__(64, 1)
void nerf_k2m(const float* __restrict__ x,
              const float* __restrict__ planes,
              const uint32_t* __restrict__ feat,
              const float* __restrict__ app_pre,
              const short* __restrict__ c0Bhi, const short* __restrict__ c0Blo,
              const short* __restrict__ c1Bhi, const short* __restrict__ c1Blo,
              const float* __restrict__ t_c2,
              float* __restrict__ out, int npts)
{
    __shared__ uint16_t ldsA[2*64*LDSH];
    __shared__ int      lds_ai[64];

    const int l = threadIdx.x;
    int n = blockIdx.x*64 + l;
    bool ok = (n < npts);
    int nc = ok ? n : (npts-1);
    const float* xr = x + (size_t)nc*7;

    {
        float av[55];
        float dx=xr[3], dy=xr[4], dz=xr[5];
        float nrm = sqrtf(dx*dx+dy*dy+dz*dz);
        float sx=dx/nrm, sy=dy/nrm, sz=dz/nrm;
        float xx=sx*sx, yy=sy*sy, zz=sz*sz, xyv=sx*sy, yzv=sy*sz, xzv=sx*sz;
        av[0]=0.28209479177387814f;
        av[1]=-0.48860251190291987f*sy;
        av[2]= 0.48860251190291987f*sz;
        av[3]=-0.48860251190291987f*sx;
        av[4]= 1.0925484305920792f*xyv;
        av[5]=-1.0925484305920792f*yzv;
        av[6]= 0.94617469575756f*zz-0.31539156525252005f;
        av[7]=-1.0925484305920792f*xzv;
        av[8]= 0.5462742152960396f*(xx-yy);
        av[9]=-0.5900435899266435f*sy*(3.f*xx-yy);
        av[10]=2.890611442640554f*xyv*sz;
        av[11]=-0.4570457994644658f*sy*(4.f*zz-xx-yy);
        av[12]=0.3731763325901154f*sz*(2.f*zz-3.f*xx-3.f*yy);
        av[13]=-0.4570457994644658f*sx*(4.f*zz-xx-yy);
        av[14]=1.445305721320277f*sz*(xx-yy);
        av[15]=-0.5900435899266435f*sx*(xx-3.f*yy);
#pragma unroll
        for (int j=0;j<15;j++) av[16+j] = __uint_as_float(feat[(size_t)j*npts + nc]);
        float pfv[24];
        plane_enc(planes, (xr[0]+1.f)*0.5f, (xr[1]+1.f)*0.5f, (xr[2]+1.f)*0.5f, pfv);
#pragma unroll
        for (int j=0;j<24;j++) av[31+j] = pfv[j];

        uint16_t* rh = &ldsA[l*LDSH];
        uint16_t* rl = &ldsA[64*LDSH + l*LDSH];
#pragma unroll
        for (int kk=0; kk<64; kk++){
            float a = (kk<55) ? av[kk] : 0.f;
            uint16_t hi = f2bf(a);
            uint16_t lo = f2bf(a - bf2f(hi));
            rh[kk] = hi; rl[kk] = lo;
        }
        lds_ai[l] = (int)xr[6];
    }
    __syncthreads();

    f32x4 acc[4][4];
    {
        const int lq = l >> 4, lr = l & 15;
#pragma unroll
        for (int mt=0; mt<4; mt++){
#pragma unroll
            for (int r=0; r<4; r++){
                int ai = lds_ai[mt*16 + lq*4 + r];
                const float* ap = app_pre + (size_t)ai*64 + lr;
#pragma unroll
                for (int nt=0; nt<4; nt++)
                    acc[mt][nt][r] = ap[nt*16];
            }
        }
    }
    {
        const int lq = l >> 4, lr = l & 15;
#pragma unroll
        for (int ks=0; ks<2; ks++){
            short8v ah[4], al[4];
#pragma unroll
            for (int mt=0; mt<4; mt++){
                const uint16_t* ph = &ldsA[(mt*16+lr)*LDSH + ks*32 + lq*8];
                ah[mt] = *reinterpret_cast<const short8v*>(ph);
                al[mt] = *reinterpret_cast<const short8v*>(ph + 64*LDSH);
            }
#pragma unroll
            for (int nt=0; nt<4; nt++){
                short8v bh = *reinterpret_cast<const short8v*>(&c0Bhi[(nt*2+ks)*512 + l*8]);
                short8v bl = *reinterpret_cast<const short8v*>(&c0Blo[(nt*2+ks)*512 + l*8]);
#pragma unroll
                for (int mt=0; mt<4; mt++){
                    acc[mt][nt] = __builtin_amdgcn_mfma_f32_16x16x32_bf16(ah[mt], bh, acc[mt][nt], 0,0,0);
                    acc[mt][nt] = __builtin_amdgcn_mfma_f32_16x16x32_bf16(ah[mt], bl, acc[mt][nt], 0,0,0);
                    acc[mt][nt] = __builtin_amdgcn_mfma_f32_16x16x32_bf16(al[mt], bh, acc[mt][nt], 0,0,0);
                }
            }
        }
    }
    __syncthreads();

    {
        const int lq = l >> 4, lr = l & 15;
#pragma unroll
        for (int mt=0; mt<4; mt++){
#pragma unroll
            for (int nt=0; nt<4; nt++){
#pragma unroll
                for (int r=0; r<4; r++){
                    float v = fmaxf(acc[mt][nt][r], 0.f);
                    uint16_t hi = f2bf(v);
                    uint16_t lo = f2bf(v - bf2f(hi));
                    int pt = mt*16 + lq*4 + r;
                    int ch = nt*16 + lr;
                    ldsA[pt*LDSH + ch] = hi;
                    ldsA[64*LDSH + pt*LDSH + ch] = lo;
                }
            }
        }
    }
    __syncthreads();

    {
        const int lq = l >> 4, lr = l & 15;
#pragma unroll
        for (int mt=0; mt<4; mt++)
#pragma unroll
            for (int nt=0; nt<4; nt++){
                acc[mt][nt][0]=0.f; acc[mt][nt][1]=0.f; acc[mt][nt][2]=0.f; acc[mt][nt][3]=0.f;
            }
#pragma unroll
        for (int ks=0; ks<2; ks++){
            short8v ah[4], al[4];
#pragma unroll
            for (int mt=0; mt<4; mt++){
                const uint16_t* ph = &ldsA[(mt*16+lr)*LDSH + ks*32 + lq*8];
                ah[mt] = *reinterpret_cast<const short8v*>(ph);
                al[mt] = *reinterpret_cast<const short8v*>(ph + 64*LDSH);
            }
#pragma unroll
            for (int nt=0; nt<4; nt++){
                short8v bh = *reinterpret_cast<const short8v*>(&c1Bhi[(nt*2+ks)*512 + l*8]);
                short8v bl = *reinterpret_cast<const short8v*>(&c1Blo[(nt*2+ks)*512 + l*8]);
#pragma unroll
                for (int mt=0; mt<4; mt++){
                    acc[mt][nt] = __builtin_amdgcn_mfma_f32_16x16x32_bf16(ah[mt], bh, acc[mt][nt], 0,0,0);
                    acc[mt][nt] = __builtin_amdgcn_mfma_f32_16x16x32_bf16(ah[mt], bl, acc[mt][nt], 0,0,0);
                    acc[mt][nt] = __builtin_amdgcn_mfma_f32_16x16x32_bf16(al[mt], bh, acc[mt][nt], 0,0,0);
                }
            }
        }
    }
    __syncthreads();

    {
        float* ldsF = reinterpret_cast<float*>(ldsA);
        const int lq = l >> 4, lr = l & 15;
#pragma unroll
        for (int mt=0; mt<4; mt++){
#pragma unroll
            for (int nt=0; nt<4; nt++){
#pragma unroll
                for (int r=0; r<4; r++){
                    int pt = mt*16 + lq*4 + r;
                    int ch = nt*16 + lr;
                    ldsF[pt*66 + ch] = fmaxf(acc[mt][nt][r], 0.f);
                }
            }
        }
        __syncthreads();

        float c0=0.f, c1=0.f, c2=0.f;
        const float* row = &ldsF[l*66];
#pragma unroll
        for (int ch=0; ch<64; ch++){
            float v = row[ch];
            float4 w = ld4(&t_c2[ch*4]);
            c0 = fmaf(w.x, v, c0);
            c1 = fmaf(w.y, v, c1);
            c2 = fmaf(w.z, v, c2);
        }
        if (ok){
            float sigma = __uint_as_float(feat[(size_t)15*npts + n]);
            float4 o4;
            o4.x = 1.f/(1.f+expf(-c0));
            o4.y = 1.f/(1.f+expf(-c1));
            o4.z = 1.f/(1.f+expf(-c2));
            o4.w = sigma;
            *reinterpret_cast<float4*>(out + (size_t)n*4) = o4;
        }
    }
}

// ===================== K12m: FUSED sigma+color MLP via MFMA =====================
// One wave per 64 points. sigma0 -> relu -> sigma1 -> (geo to color0 A-tile,
// sigma column to sig[]) -> color0 -> relu -> color1 -> relu -> color2.
__global__ __launch_bounds__(64, 1)
void nerf_k12m(const float* __restrict__ x,
               const float* __restrict__ planes,
               const uint32_t* __restrict__ feat,
               const float* __restrict__ app_pre,
               const short* __restrict__ s0Bhi, const short* __restrict__ s0Blo,
               const short* __restrict__ s1Bhi, const short* __restrict__ s1Blo,
               const short* __restrict__ c0Bhi, const short* __restrict__ c0Blo,
               const short* __restrict__ c1Bhi, const short* __restrict__ c1Blo,
               const float* __restrict__ t_c2,
               float* __restrict__ out, int npts)
{
    __shared__ uint16_t ldsA[2*64*LDSH];
    __shared__ float    sig[64];
    __shared__ int      lds_ai[64];

    const int l = threadIdx.x;
    const int lq = l >> 4, lr = l & 15;
    int n = blockIdx.x*64 + l;
    bool ok = (n < npts);
    int nc = ok ? n : (npts-1);
    const float* xr = x + (size_t)nc*7;

    // Per-lane values kept in registers across the sigma phases:
    float pfv[24];
    float sh[16];
    {
        float dx=xr[3], dy=xr[4], dz=xr[5];
        float nrm = sqrtf(dx*dx+dy*dy+dz*dz);
        float sx=dx/nrm, sy=dy/nrm, sz=dz/nrm;
        float xx=sx*sx, yy=sy*sy, zz=sz*sz, xyv=sx*sy, yzv=sy*sz, xzv=sx*sz;
        sh[0]=0.28209479177387814f;
        sh[1]=-0.48860251190291987f*sy;
        sh[2]= 0.48860251190291987f*sz;
        sh[3]=-0.48860251190291987f*sx;
        sh[4]= 1.0925484305920792f*xyv;
        sh[5]=-1.0925484305920792f*yzv;
        sh[6]= 0.94617469575756f*zz-0.31539156525252005f;
        sh[7]=-1.0925484305920792f*xzv;
        sh[8]= 0.5462742152960396f*(xx-yy);
        sh[9]=-0.5900435899266435f*sy*(3.f*xx-yy);
        sh[10]=2.890611442640554f*xyv*sz;
        sh[11]=-0.4570457994644658f*sy*(4.f*zz-xx-yy);
        sh[12]=0.3731763325901154f*sz*(2.f*zz-3.f*xx-3.f*yy);
        sh[13]=-0.4570457994644658f*sx*(4.f*zz-xx-yy);
        sh[14]=1.445305721320277f*sz*(xx-yy);
        sh[15]=-0.5900435899266435f*sx*(xx-3.f*yy);
        plane_enc(planes, (xr[0]+1.f)*0.5f, (xr[1]+1.f)*0.5f, (xr[2]+1.f)*0.5f, pfv);
        lds_ai[l] = (int)xr[6];
    }

    // ---- phase 1: sigma0 A-tile. cols 0..31 hash (bf16-exact, u32 store; lo=0),
    //      cols 32..55 planes hi/lo, 56..63 zero. ----
    {
        uint16_t* rh = &ldsA[l*LDSH];
        uint16_t* rl = &ldsA[64*LDSH + l*LDSH];
#pragma unroll
        for (int lv=0; lv<16; lv++){
            uint32_t f = feat[(size_t)lv*npts + nc];
            *reinterpret_cast<uint32_t*>(&rh[2*lv]) = f;
            *reinterpret_cast<uint32_t*>(&rl[2*lv]) = 0u;
        }
#pragma unroll
        for (int j=0;j<24;j++){
            float a = pfv[j];
            uint16_t hi = f2bf(a);
            rh[32+j] = hi;
            rl[32+j] = f2bf(a - bf2f(hi));
        }
#pragma unroll
        for (int j=56;j<64;j++){ rh[j]=0; rl[j]=0; }
    }
    __syncthreads();

    // ---- phase 2: sigma0 MFMA (acc=0 init). ks=0: A-lo==0 -> skip al*bh term. ----
    f32x4 acc[4][4];
#pragma unroll
    for (int mt=0; mt<4; mt++)
#pragma unroll
        for (int nt=0; nt<4; nt++){
            acc[mt][nt][0]=0.f; acc[mt][nt][1]=0.f; acc[mt][nt][2]=0.f; acc[mt][nt][3]=0.f;
        }
#pragma unroll
    for (int ks=0; ks<2; ks++){
        short8v ah[4], al[4];
#pragma unroll
        for (int mt=0; mt<4; mt++){
            const uint16_t* ph = &ldsA[(mt*16+lr)*LDSH + ks*32 + lq*8];
            ah[mt] = *reinterpret_cast<const short8v*>(ph);
            al[mt] = *reinterpret_cast<const short8v*>(ph + 64*LDSH);
        }
#pragma unroll
        for (int nt=0; nt<4; nt++){
            short8v bh = *reinterpret_cast<const short8v*>(&s0Bhi[(nt*2+ks)*512 + l*8]);
            short8v bl = *reinterpret_cast<const short8v*>(&s0Blo[(nt*2+ks)*512 + l*8]);
#pragma unroll
            for (int mt=0; mt<4; mt++){
                acc[mt][nt] = __builtin_amdgcn_mfma_f32_16x16x32_bf16(ah[mt], bh, acc[mt][nt], 0,0,0);
                acc[mt][nt] = __builtin_amdgcn_mfma_f32_16x16x32_bf16(ah[mt], bl, acc[mt][nt], 0,0,0);
                if (ks==1)
                    acc[mt][nt] = __builtin_amdgcn_mfma_f32_16x16x32_bf16(al[mt], bh, acc[mt][nt], 0,0,0);
            }
        }
    }
    __syncthreads();

    // ---- phase 3: relu(h0) repack hi/lo for sigma1 ----
#pragma unroll
    for (int mt=0; mt<4; mt++){
#pragma unroll
        for (int nt=0; nt<4; nt++){
#pragma unroll
            for (int r=0; r<4; r++){
                float v = fmaxf(acc[mt][nt][r], 0.f);
                uint16_t hi = f2bf(v);
                int pt = mt*16 + lq*4 + r;
                int ch = nt*16 + lr;
                ldsA[pt*LDSH + ch] = hi;
                ldsA[64*LDSH + pt*LDSH + ch] = f2bf(v - bf2f(hi));
            }
        }
    }
    __syncthreads();

    // ---- phase 4: sigma1 MFMA (out=16, 1 nt tile) ----
    f32x4 acc2[4];
#pragma unroll
    for (int mt=0; mt<4; mt++){ acc2[mt][0]=0.f; acc2[mt][1]=0.f; acc2[mt][2]=0.f; acc2[mt][3]=0.f; }
#pragma unroll
    for (int ks=0; ks<2; ks++){
        short8v bh = *reinterpret_cast<const short8v*>(&s1Bhi[ks*512 + l*8]);
        short8v bl = *reinterpret_cast<const short8v*>(&s1Blo[ks*512 + l*8]);
#pragma unroll
        for (int mt=0; mt<4; mt++){
            const uint16_t* ph = &ldsA[(mt*16+lr)*LDSH + ks*32 + lq*8];
            short8v ah = *reinterpret_cast<const short8v*>(ph);
            short8v al = *reinterpret_cast<const short8v*>(ph + 64*LDSH);
            acc2[mt] = __builtin_amdgcn_mfma_f32_16x16x32_bf16(ah, bh, acc2[mt], 0,0,0);
            acc2[mt] = __builtin_amdgcn_mfma_f32_16x16x32_bf16(ah, bl, acc2[mt], 0,0,0);
            acc2[mt] = __builtin_amdgcn_mfma_f32_16x16x32_bf16(al, bh, acc2[mt], 0,0,0);
        }
    }
    __syncthreads();   // done reading h0 tiles; ldsA now rewritten as color0 A

    // ---- phase 5: build color0 A-tile: sh(0..15) + geo(16..30) + pf(31..54) ----
    {
        // own row: sh + pf + pads
        uint16_t* rh = &ldsA[l*LDSH];
        uint16_t* rl = &ldsA[64*LDSH + l*LDSH];
#pragma unroll
        for (int j=0;j<16;j++){
            float a = sh[j];
            uint16_t hi = f2bf(a);
            rh[j] = hi; rl[j] = f2bf(a - bf2f(hi));
        }
#pragma unroll
        for (int j=0;j<24;j++){
            float a = pfv[j];
            uint16_t hi = f2bf(a);
            rh[31+j] = hi; rl[31+j] = f2bf(a - bf2f(hi));
        }
#pragma unroll
        for (int j=55;j<64;j++){ rh[j]=0; rl[j]=0; }
        // D-mapped: h1 -> geo cols 16..30, sigma col -> sig[]
        int ch = lr;   // output channel of sigma1
#pragma unroll
        for (int mt=0; mt<4; mt++){
#pragma unroll
            for (int r=0; r<4; r++){
                int pt = mt*16 + lq*4 + r;
                float v = acc2[mt][r];
                if (ch == 0){
                    sig[pt] = v;
                } else {
                    uint16_t hi = f2bf(v);
                    ldsA[pt*LDSH + 16 + (ch-1)] = hi;
                    ldsA[64*LDSH + pt*LDSH + 16 + (ch-1)] = f2bf(v - bf2f(hi));
                }
            }
        }
    }
    __syncthreads();

    // ---- phase 6: color0 MFMA (app_pre C-init) ----
#pragma unroll
    for (int mt=0; mt<4; mt++){
#pragma unroll
        for (int r=0; r<4; r++){
            int ai = lds_ai[mt*16 + lq*4 + r];
            const float* ap = app_pre + (size_t)ai*64 + lr;
#pragma unroll
            for (int nt=0; nt<4; nt++)
                acc[mt][nt][r] = ap[nt*16];
        }
    }
#pragma unroll
    for (int ks=0; ks<2; ks++){
        short8v ah[4], al[4];
#pragma unroll
        for (int mt=0; mt<4; mt++){
            const uint16_t* ph = &ldsA[(mt*16+lr)*LDSH + ks*32 + lq*8];
            ah[mt] = *reinterpret_cast<const short8v*>(ph);
            al[mt] = *reinterpret_cast<const short8v*>(ph + 64*LDSH);
        }
#pragma unroll
        for (int nt=0; nt<4; nt++){
            short8v bh = *reinterpret_cast<const short8v*>(&c0Bhi[(nt*2+ks)*512 + l*8]);
            short8v bl = *reinterpret_cast<const short8v*>(&c0Blo[(nt*2+ks)*512 + l*8]);
#pragma unroll
            for (int mt=0; mt<4; mt++){
                acc[mt][nt] = __builtin_amdgcn_mfma_f32_16x16x32_bf16(ah[mt], bh, acc[mt][nt], 0,0,0);
                acc[mt][nt] = __builtin_amdgcn_mfma_f32_16x16x32_bf16(ah[mt], bl, acc[mt][nt], 0,0,0);
                acc[mt][nt] = __builtin_amdgcn_mfma_f32_16x16x32_bf16(al[mt], bh, acc[mt][nt], 0,0,0);
            }
        }
    }
    __syncthreads();

    // ---- phase 7: relu repack, color1 MFMA ----
#pragma unroll
    for (int mt=0; mt<4; mt++){
#pragma unroll
        for (int nt=0; nt<4; nt++){
#pragma unroll
            for (int r=0; r<4; r++){
                float v = fmaxf(acc[mt][nt][r], 0.f);
                uint16_t hi = f2bf(v);
                int pt = mt*16 + lq*4 + r;
                int ch = nt*16 + lr;
                ldsA[pt*LDSH + ch] = hi;
                ldsA[64*LDSH + pt*LDSH + ch] = f2bf(v - bf2f(hi));
            }
        }
    }
    __syncthreads();

#pragma unroll
    for (int mt=0; mt<4; mt++)
#pragma unroll
        for (int nt=0; nt<4; nt++){
            acc[mt][nt][0]=0.f; acc[mt][nt][1]=0.f; acc[mt][nt][2]=0.f; acc[mt][nt][3]=0.f;
        }
#pragma unroll
    for (int ks=0; ks<2; ks++){
        short8v ah[4], al[4];
#pragma unroll
        for (int mt=0; mt<4; mt++){
            const uint16_t* ph = &ldsA[(mt*16+lr)*LDSH + ks*32 + lq*8];
            ah[mt] = *reinterpret_cast<const short8v*>(ph);
            al[mt] = *reinterpret_cast<const short8v*>(ph + 64*LDSH);
        }
#pragma unroll
        for (int nt=0; nt<4; nt++){
            short8v bh = *reinterpret_cast<const short8v*>(&c1Bhi[(nt*2+ks)*512 + l*8]);
            short8v bl = *reinterpret_cast<const short8v*>(&c1Blo[(nt*2+ks)*512 + l*8]);
#pragma unroll
            for (int mt=0; mt<4; mt++){
                acc[mt][nt] = __builtin_amdgcn_mfma_f32_16x16x32_bf16(ah[mt], bh, acc[mt][nt], 0,0,0);
                acc[mt][nt] = __builtin_amdgcn_mfma_f32_16x16x32_bf16(ah[mt], bl, acc[mt][nt], 0,0,0);
                acc[mt][nt] = __builtin_amdgcn_mfma_f32_16x16x32_bf16(al[mt], bh, acc[mt][nt], 0,0,0);
            }
        }
    }
    __syncthreads();

    // ---- phase 8: relu -> LDS f32, color2 + sigmoid + sigma + store ----
    {
        float* ldsF = reinterpret_cast<float*>(ldsA);
#pragma unroll
        for (int mt=0; mt<4; mt++){
#pragma unroll
            for (int nt=0; nt<4; nt++){
#pragma unroll
                for (int r=0; r<4; r++){
                    int pt = mt*16 + lq*4 + r;
                    int ch = nt*16 + lr;
                    ldsF[pt*66 + ch] = fmaxf(acc[mt][nt][r], 0.f);
                }
            }
        }
        __syncthreads();

        float c0=0.f, c1=0.f, c2=0.f;
        const float* row = &ldsF[l*66];
#pragma unroll
        for (int ch=0; ch<64; ch++){
            float v = row[ch];
            float4 w = ld4(&t_c2[ch*4]);
            c0 = fmaf(w.x, v, c0);
            c1 = fmaf(w.y, v, c1);
            c2 = fmaf(w.z, v, c2);
        }
        if (ok){
            float sg = fminf(fmaxf(sig[l], -15.f), 15.f);
            float4 o4;
            o4.x = 1.f/(1.f+expf(-c0));
            o4.y = 1.f/(1.f+expf(-c1));
            o4.z = 1.f/(1.f+expf(-c2));
            o4.w = expf(sg);
            *reinterpret_cast<float4*>(out + (size_t)n*4) = o4;
        }
    }
}

// ===================== fallback single kernel =====================
__global__ __launch_bounds__(256, 1)
void nerf_fwd(const float* __restrict__ x,
              const float* __restrict__ hash_tables,
              const float* __restrict__ planes,
              const float* __restrict__ embed_a,
              const float* __restrict__ w_sigma0,
              const float* __restrict__ w_sigma1,
              const float* __restrict__ w_color0,
              const float* __restrict__ w_color1,
              const float* __restrict__ w_color2,
              float* __restrict__ out,
              ResArr res, int npts)
{
    __shared__ float s_ws0T[56*64];
    __shared__ float s_ws1T[64*16];
    __shared__ float s_wc0T[103*64];
    __shared__ float s_wc1T[64*64];
    __shared__ float s_wc2T[64*4];

    for (int i = threadIdx.x; i < 56*64;  i += 256){ int k=i>>6, o=i&63; s_ws0T[i] = w_sigma0[o*56+k]; }
    for (int i = threadIdx.x; i < 64*16;  i += 256){ int k=i>>4, j=i&15; s_ws1T[i] = w_sigma1[j*64+k]; }
    for (int i = threadIdx.x; i < 103*64; i += 256){ int k=i>>6, o=i&63; s_wc0T[i] = w_color0[o*103+k]; }
    for (int i = threadIdx.x; i < 64*64;  i += 256){ int k=i>>6, o=i&63; s_wc1T[i] = w_color1[o*64+k]; }
    for (int i = threadIdx.x; i < 64*4;   i += 256){ int k=i>>2, o=i&3;  s_wc2T[i] = (o<3)? w_color2[o*64+k] : 0.f; }
    __syncthreads();

    int n = blockIdx.x*256 + threadIdx.x;
    if (n >= npts) return;

    const float* xr = x + (size_t)n*7;
    float px=xr[0], py=xr[1], pz=xr[2];
    float dx=xr[3], dy=xr[4], dz=xr[5];
    float appf = xr[6];
    float p0=(px+1.f)*0.5f, p1=(py+1.f)*0.5f, p2=(pz+1.f)*0.5f;

    float acc[HID];
#pragma unroll
    for (int o=0;o<HID;o++) acc[o]=0.f;

    const float2* tabs = reinterpret_cast<const float2*>(hash_tables);
    for (int l=0; l<NLEV; l++){
        float R = res.v[l];
        float ax=p0*R, ay=p1*R, az=p2*R;
        float fx=floorf(ax), fy=floorf(ay), fz=floorf(az);
        float rx=ax-fx, ry=ay-fy, rz=az-fz;
        uint32_t ix=(uint32_t)fx, iy=(uint32_t)fy, iz=(uint32_t)fz;
        const float2* tab = tabs + (size_t)l*TSIZE;
        uint32_t hx0=ix,               hx1=ix+1u;
        uint32_t hy0=iy*2654435761u,   hy1=(iy+1u)*2654435761u;
        uint32_t hz0=iz*805459861u,    hz1=(iz+1u)*805459861u;
        float wx0=1.f-rx, wx1=rx, wy0=1.f-ry, wy1=ry, wz0=1.f-rz, wz1=rz;
        float f0=0.f, f1=0.f;
#pragma unroll
        for (int c=0;c<8;c++){
            uint32_t hxx=(c&4)?hx1:hx0;
            uint32_t hyy=(c&2)?hy1:hy0;
            uint32_t hzz=(c&1)?hz1:hz0;
            uint32_t idx=(hxx^hyy^hzz)&(TSIZE-1u);
            float2 t = tab[idx];
            float w = ((c&4)?wx1:wx0)*((c&2)?wy1:wy0)*((c&1)?wz1:wz0);
            f0 = fmaf(w,t.x,f0);
            f1 = fmaf(w,t.y,f1);
        }
        AXPY64(acc, &s_ws0T[(2*l+0)*64], f0);
        AXPY64(acc, &s_ws0T[(2*l+1)*64], f1);
    }

    float pfv[24];
    plane_enc(planes, p0, p1, p2, pfv);
#pragma unroll
    for (int j=0;j<24;j++){
        AXPY64(acc, &s_ws0T[(32+j)*64], pfv[j]);
    }

    float h1[16];
#pragma unroll
    for (int j=0;j<16;j++) h1[j]=0.f;
#pragma unroll
    for (int k=0;k<HID;k++){
        float v = fmaxf(acc[k], 0.f);
        const float* wr = &s_ws1T[k*16];
#pragma unroll
        for (int j=0;j<16;j+=4){
            float4 w=ld4(wr+j);
            h1[j+0]=fmaf(w.x,v,h1[j+0]); h1[j+1]=fmaf(w.y,v,h1[j+1]);
            h1[j+2]=fmaf(w.z,v,h1[j+2]); h1[j+3]=fmaf(w.w,v,h1[j+3]);
        }
    }
    float sg = fminf(fmaxf(h1[0], -15.f), 15.f);
    float sigma = expf(sg);

#pragma unroll
    for (int o=0;o<HID;o++) acc[o]=0.f;

    float nrm = sqrtf(dx*dx+dy*dy+dz*dz);
    float sx=dx/nrm, sy=dy/nrm, sz=dz/nrm;
    float xx=sx*sx, yy=sy*sy, zz=sz*sz, xyv=sx*sy, yzv=sy*sz, xzv=sx*sz;
    float sh[16];
    sh[0]=0.28209479177387814f;
    sh[1]=-0.48860251190291987f*sy;
    sh[2]= 0.48860251190291987f*sz;
    sh[3]=-0.48860251190291987f*sx;
    sh[4]= 1.0925484305920792f*xyv;
    sh[5]=-1.0925484305920792f*yzv;
    sh[6]= 0.94617469575756f*zz-0.31539156525252005f;
    sh[7]=-1.0925484305920792f*xzv;
    sh[8]= 0.5462742152960396f*(xx-yy);
    sh[9]=-0.5900435899266435f*sy*(3.f*xx-yy);
    sh[10]=2.890611442640554f*xyv*sz;
    sh[11]=-0.4570457994644658f*sy*(4.f*zz-xx-yy);
    sh[12]=0.3731763325901154f*sz*(2.f*zz-3.f*xx-3.f*yy);
    sh[13]=-0.4570457994644658f*sx*(4.f*zz-xx-yy);
    sh[14]=1.445305721320277f*sz*(xx-yy);
    sh[15]=-0.5900435899266435f*sx*(xx-3.f*yy);
#pragma unroll
    for (int k=0;k<16;k++){
        AXPY64(acc, &s_wc0T[k*64], sh[k]);
    }
#pragma unroll
    for (int j=0;j<15;j++){
        AXPY64(acc, &s_wc0T[(16+j)*64], h1[1+j]);
    }
    {
        int ai = (int)appf;
        const float* ar = embed_a + (size_t)ai*48;
        for (int q=0;q<12;q++){
            float4 av = ld4(ar + q*4);
            const float* wc = &s_wc0T[(31+q*4)*64];
            AXPY64(acc, wc,       av.x);
            AXPY64(acc, wc+64,    av.y);
            AXPY64(acc, wc+128,   av.z);
            AXPY64(acc, wc+192,   av.w);
        }
    }
#pragma unroll
    for (int j=0;j<24;j++){
        AXPY64(acc, &s_wc0T[(79+j)*64], pfv[j]);
    }

    float acc2[HID];
#pragma unroll
    for (int o=0;o<HID;o++) acc2[o]=0.f;
#pragma unroll
    for (int k=0;k<HID;k++){
        float v = fmaxf(acc[k], 0.f);
        AXPY64(acc2, &s_wc1T[k*64], v);
    }

    float c0a=0.f, c1a=0.f, c2a=0.f;
#pragma unroll
    for (int k=0;k<HID;k++){
        float v = fmaxf(acc2[k], 0.f);
        float4 w = ld4(&s_wc2T[k*4]);
        c0a=fmaf(w.x,v,c0a); c1a=fmaf(w.y,v,c1a); c2a=fmaf(w.z,v,c2a);
    }
    float4 o4;
    o4.x = 1.f/(1.f+expf(-c0a));
    o4.y = 1.f/(1.f+expf(-c1a));
    o4.z = 1.f/(1.f+expf(-c2a));
    o4.w = sigma;
    *reinterpret_cast<float4*>(out + (size_t)n*4) = o4;
}

extern "C" void kernel_launch(void* const* d_in, const int* in_sizes, int n_in,
                              void* d_out, int out_size, void* d_ws, size_t ws_size,
                              hipStream_t stream) {
    const float* x        = (const float*)d_in[0];
    const float* ht       = (const float*)d_in[1];
    const float* planes   = (const float*)d_in[2];
    const float* embed_a  = (const float*)d_in[3];
    const float* w_sigma0 = (const float*)d_in[4];
    const float* w_sigma1 = (const float*)d_in[5];
    const float* w_color0 = (const float*)d_in[6];
    const float* w_color1 = (const float*)d_in[7];
    const float* w_color2 = (const float*)d_in[8];
    float* out = (float*)d_out;

    int npts = in_sizes[0] / 7;

    ResArr res;
    double b = exp((log(2048.0) - log(16.0)) / 15.0);
    for (int l=0; l<NLEV; l++)
        res.v[l] = (float)floor(16.0 * pow(b, (double)l));

    // ws layout (bytes)
    const size_t OFF_S0  = 0;
    const size_t OFF_S1  = OFF_S0 + 56*64*4;
    const size_t OFF_C2  = OFF_S1 + 64*16*4;
    const size_t OFF_AP  = OFF_C2 + 64*4*4;
    const size_t OFF_B0H = OFF_AP + 1024*64*4;
    const size_t OFF_B0L = OFF_B0H + 4096*2;
    const size_t OFF_B1H = OFF_B0L + 4096*2;
    const size_t OFF_B1L = OFF_B1H + 4096*2;
    const size_t OFF_SB0H= OFF_B1L + 4096*2;
    const size_t OFF_SB0L= OFF_SB0H + 4096*2;
    const size_t OFF_SB1H= OFF_SB0L + 4096*2;
    const size_t OFF_SB1L= OFF_SB1H + 1024*2;
    const size_t OFF_SMALL_END = OFF_SB1L + 1024*2;
    size_t feat_bytes = (size_t)npts * 16 * sizeof(uint32_t);
    size_t pp_bytes   = (size_t)npts * 16;
    size_t tb_bytes   = (size_t)16 * TSIZE * 4;      // 32MB

    const size_t OFF_PP   = OFF_SMALL_END;
    const size_t OFF_TB   = OFF_PP + pp_bytes;
    const size_t OFF_FEAT2= OFF_TB + tb_bytes;
    const size_t OFF_FEAT1= OFF_SMALL_END;

    bool full_path = (ws_size >= OFF_FEAT2 + feat_bytes);
    bool mid_path  = (ws_size >= OFF_FEAT1 + feat_bytes);

    if (full_path || mid_path) {
        char* base = (char*)d_ws;
        float* t_s0  = (float*)(base + OFF_S0);
        float* t_s1  = (float*)(base + OFF_S1);
        float* t_c2  = (float*)(base + OFF_C2);
        float* a_pre = (float*)(base + OFF_AP);
        short* c0Bhi = (short*)(base + OFF_B0H);
        short* c0Blo = (short*)(base + OFF_B0L);
        short* c1Bhi = (short*)(base + OFF_B1H);
        short* c1Blo = (short*)(base + OFF_B1L);
        short* s0Bhi = (short*)(base + OFF_SB0H);
        short* s0Blo = (short*)(base + OFF_SB0L);
        short* s1Bhi = (short*)(base + OFF_SB1H);
        short* s1Blo = (short*)(base + OFF_SB1L);

        hipLaunchKernelGGL(nerf_ktrans, dim3(1), dim3(256), 0, stream,
                           w_sigma0, w_sigma1, w_color0, w_color1, w_color2,
                           t_s0, t_s1, t_c2, c0Bhi, c0Blo, c1Bhi, c1Blo,
                           s0Bhi, s0Blo, s1Bhi, s1Blo);
        hipLaunchKernelGGL(nerf_kpre, dim3(1024), dim3(64), 0, stream,
                           embed_a, w_color0, a_pre);

        if (full_path) {
            float4*   pp      = (float4*)(base + OFF_PP);
            uint32_t* tabs_bf = (uint32_t*)(base + OFF_TB);
            uint32_t* feat    = (uint32_t*)(base + OFF_FEAT2);

            int total = 16 * (int)TSIZE;
            hipLaunchKernelGGL(nerf_krepack, dim3((total+255)/256), dim3(256), 0, stream,
                               (const float2*)ht, tabs_bf, total);
            hipLaunchKernelGGL(nerf_kprep, dim3((npts+255)/256), dim3(256), 0, stream,
                               x, pp, npts);

            int chunks = (npts + 1023) / 1024;
            hipLaunchKernelGGL(nerf_k0b, dim3(8*chunks), dim3(256), 0, stream,
                               pp, tabs_bf, feat, res, npts, 0);
            hipLaunchKernelGGL(nerf_k0b, dim3(8*chunks), dim3(256), 0, stream,
                               pp, tabs_bf, feat, res, npts, 8);

            int gm = (npts + 63) / 64;
            hipLaunchKernelGGL(nerf_k12m, dim3(gm), dim3(64), 0, stream,
                               x, planes, feat, a_pre,
                               s0Bhi, s0Blo, s1Bhi, s1Blo,
                               c0Bhi, c0Blo, c1Bhi, c1Blo, t_c2, out, npts);
        } else {
            uint32_t* feat = (uint32_t*)(base + OFF_FEAT1);
            int chunks = (npts + 511) / 512;
            hipLaunchKernelGGL(nerf_k0, dim3(8*chunks), dim3(256), 0, stream,
                               x, ht, feat, res, npts, 0);
            hipLaunchKernelGGL(nerf_k0, dim3(8*chunks), dim3(256), 0, stream,
                               x, ht, feat, res, npts, 8);
            int g = (npts + 255) / 256;
            hipLaunchKernelGGL(nerf_k1s, dim3(g), dim3(256), 0, stream,
                               x, planes, feat, t_s0, t_s1, npts);
            int gm = (npts + 63) / 64;
            hipLaunchKernelGGL(nerf_k2m, dim3(gm), dim3(64), 0, stream,
                               x, planes, feat, a_pre,
                               c0Bhi, c0Blo, c1Bhi, c1Blo, t_c2, out, npts);
        }
    } else {
        int grid = (npts + 255) / 256;
        hipLaunchKernelGGL(nerf_fwd, dim3(grid), dim3(256), 0, stream,
                           x, ht, planes, embed_a,
                           w_sigma0, w_sigma1, w_color0, w_color1, w_color2,
                           out, res, npts);
    }
}